// Round 5
// baseline (1478.068 us; speedup 1.0000x reference)
//
#include <hip/hip_runtime.h>
#include <hip/hip_bf16.h>

#define B 2
#define L 2048
#define D 1024
#define H 16
#define HD 64
#define LH 8
#define NEG_INF -1e30f

typedef __hip_bfloat16 bf16;
typedef unsigned short ushort_t;
typedef short bf16x8 __attribute__((ext_vector_type(8)));
typedef unsigned short us8 __attribute__((ext_vector_type(8)));
typedef float f32x4 __attribute__((ext_vector_type(4)));

#define MFMA16(a, b, c) __builtin_amdgcn_mfma_f32_16x16x32_bf16((a), (b), (c), 0, 0, 0)

// in-wave LDS fence: drain this wave's ds ops, pin scheduler (rule #18)
#define LGKM0_FENCE()                                     \
  do {                                                    \
    asm volatile("s_waitcnt lgkmcnt(0)" ::: "memory");    \
    __builtin_amdgcn_sched_barrier(0);                    \
  } while (0)

template<typename T> struct IsF32;
template<> struct IsF32<float> { static constexpr int value = 1; };
template<> struct IsF32<bf16>  { static constexpr int value = 0; };

__device__ __forceinline__ float ldf(const float* p, size_t i) { return p[i]; }
__device__ __forceinline__ float ldf(const bf16* p, size_t i) { return __bfloat162float(p[i]); }

__device__ __forceinline__ float4 ld4(const float* p, size_t i) {
  return *reinterpret_cast<const float4*>(p + i);
}
__device__ __forceinline__ float4 ld4(const bf16* p, size_t i) {
  ushort4 u = *reinterpret_cast<const ushort4*>(p + i);
  float4 f;
  f.x = __uint_as_float(((unsigned)u.x) << 16);
  f.y = __uint_as_float(((unsigned)u.y) << 16);
  f.z = __uint_as_float(((unsigned)u.z) << 16);
  f.w = __uint_as_float(((unsigned)u.w) << 16);
  return f;
}
__device__ __forceinline__ ushort_t bfh(float v) {
  bf16 h = __float2bfloat16(v);
  return *reinterpret_cast<ushort_t*>(&h);
}
__device__ __forceinline__ float bf2f(ushort_t u) {
  return __uint_as_float(((unsigned)u) << 16);
}
__device__ __forceinline__ void stf(float* p, size_t i, float v) { p[i] = v; }
__device__ __forceinline__ void stf(bf16* p, size_t i, float v) { p[i] = __float2bfloat16(v); }

// XOR-swizzled LDS addressing for the P slice: 64-ushort (128 B) rows,
// 8 slots of 8 ushorts (16 B); slot' = slot ^ (row & 7).
__device__ __forceinline__ int swz(int row, int slot) {
  return row * 64 + (((slot ^ (row & 7)) & 7) << 3);
}
__device__ __forceinline__ int swzc(int row, int c) {   // per-ushort column c
  return row * 64 + (((((c >> 3) ^ row) & 7) << 3) | (c & 7));
}

// Runtime dtype detection: fp32 data reinterpreted as u16 pairs shows large
// "exponent" fields in low halves with prob ~1/3; bf16 N(0,1) never does.
__global__ void detect_dtype_kernel(const unsigned short* __restrict__ x,
                                    int* __restrict__ flag) {
  int bad = 0;
  for (int i = threadIdx.x; i < 1024; i += 64) {
    if (((x[i] >> 7) & 0xFF) >= 170) bad = 1;
  }
  unsigned long long m = __ballot(bad);
  if (threadIdx.x == 0) *flag = (m != 0ULL) ? 1 : 0;
}

// ---------------- prep: split fp32 array into bf16 hi/lo planes ----------------
__global__ __launch_bounds__(256)
void split_f32_kernel(const int* __restrict__ flag, int want,
                      const float* __restrict__ in,
                      ushort_t* __restrict__ hp, ushort_t* __restrict__ lp, int n4) {
  if (*flag != want) return;
  int i = blockIdx.x * 256 + threadIdx.x;
  const int stride = gridDim.x * 256;
  for (; i < n4; i += stride) {
    float4 v = *reinterpret_cast<const float4*>(in + 4 * (size_t)i);
    ushort4 h, l;
    h.x = bfh(v.x); l.x = bfh(v.x - bf2f(h.x));
    h.y = bfh(v.y); l.y = bfh(v.y - bf2f(h.y));
    h.z = bfh(v.z); l.z = bfh(v.z - bf2f(h.z));
    h.w = bfh(v.w); l.w = bfh(v.w - bf2f(h.w));
    *reinterpret_cast<ushort4*>(hp + 4 * (size_t)i) = h;
    *reinterpret_cast<ushort4*>(lp + 4 * (size_t)i) = l;
  }
}

// ---------------- prep: transpose W [K][N] -> Wt [N][K], split to bf16 hi/lo ----
// grid (16,16,4): z=0..2 -> Wq/Wk/Wv into base (+lo for z<lo_upto); z=3 -> Wo
// hi-only into baseWo (dedicated slot so it survives attn's scratch overwrite).
template<typename T>
__global__ __launch_bounds__(256)
void transW_kernel(const int* __restrict__ flag,
                   const T* __restrict__ W0, const T* __restrict__ W1,
                   const T* __restrict__ W2, const T* __restrict__ W3,
                   ushort_t* __restrict__ base, ushort_t* __restrict__ baseWo,
                   int lo_upto) {
  if (*flag != IsF32<T>::value) return;
  const int z = blockIdx.z;
  const T* W = z == 0 ? W0 : (z == 1 ? W1 : (z == 2 ? W2 : W3));
  ushort_t* hp = (z < 3) ? (base + (size_t)z * 2097152) : baseWo;
  ushort_t* lp = hp + 1048576;
  const bool wl_ = IsF32<T>::value && (z < lo_upto);
  __shared__ float ts[64][69];
  const int k0 = blockIdx.x * 64, n0 = blockIdx.y * 64;
  const int t = threadIdx.x;
  #pragma unroll
  for (int p = 0; p < 4; ++p) {
    int r = p * 16 + (t >> 4);
    int c = (t & 15) * 4;
    float4 v = ld4(W, (size_t)(k0 + r) * D + n0 + c);
    ts[r][c] = v.x; ts[r][c + 1] = v.y; ts[r][c + 2] = v.z; ts[r][c + 3] = v.w;
  }
  __syncthreads();
  #pragma unroll
  for (int p = 0; p < 4; ++p) {
    int n = p * 16 + (t >> 4);
    int k4 = (t & 15) * 4;
    ushort4 h, l;
    float a0 = ts[k4][n], a1 = ts[k4 + 1][n], a2 = ts[k4 + 2][n], a3 = ts[k4 + 3][n];
    h.x = bfh(a0); l.x = bfh(a0 - bf2f(h.x));
    h.y = bfh(a1); l.y = bfh(a1 - bf2f(h.y));
    h.z = bfh(a2); l.z = bfh(a2 - bf2f(h.z));
    h.w = bfh(a3); l.w = bfh(a3 - bf2f(h.w));
    size_t o = (size_t)(n0 + n) * D + k0 + k4;
    *reinterpret_cast<ushort4*>(hp + o) = h;
    if (wl_) *reinterpret_cast<ushort4*>(lp + o) = l;
  }
}

// ---------------- Kernel 1: fused QKV projection (MFMA GEMM) -------------------
// 1536 blocks of 256 (XCD-swizzled). Q,K: 3-product split (fp32 path);
// V: 1-product. Writes Q/K hi+lo planes [B,H,L,HD], V^T hi plane [B,H,HD,L].
template<typename T, int NSA>
__global__ __launch_bounds__(256)
void proj_kernel(const int* __restrict__ flag,
                 const ushort_t* __restrict__ xA, const ushort_t* __restrict__ xAl,
                 const ushort_t* __restrict__ wbase,
                 const T* __restrict__ bq, const T* __restrict__ bk,
                 const T* __restrict__ bv,
                 ushort_t* __restrict__ qh, ushort_t* __restrict__ ql,
                 ushort_t* __restrict__ kh, ushort_t* __restrict__ kl,
                 ushort_t* __restrict__ vth) {
  if (*flag != IsF32<T>::value) return;
  const int bid = blockIdx.x;
  const int xcd = bid & 7, slot = bid >> 3;       // 192 slots
  const int cm = xcd + 8 * (slot >> 6);           // 0..23 (z, coltile)
  const int z = cm >> 3, ct = cm & 7;
  const int strip = slot & 63;
  const int col0 = ct * 128;
  const int lane = threadIdx.x & 63, w = threadIdx.x >> 6;
  const int t0 = strip * 64 + w * 16;
  const int m = lane & 15, hi = lane >> 4;
  const ushort_t* wh = wbase + (size_t)z * 2097152;
  const ushort_t* wl = wh + 1048576;
  const T* bias = z == 0 ? bq : (z == 1 ? bk : bv);
  const bool full = (NSA == 2) && (z != 2);   // 3-product for Q,K on fp32 path

  f32x4 acc[8] = {};
  const size_t arow = (size_t)(t0 + m) * D + hi * 8;
  for (int kc = 0; kc < 32; ++kc) {
    const int ko = kc * 32;
    bf16x8 ah = *reinterpret_cast<const bf16x8*>(xA + arow + ko);
    bf16x8 al;
    if (full) al = *reinterpret_cast<const bf16x8*>(xAl + arow + ko);
    #pragma unroll
    for (int nt = 0; nt < 8; ++nt) {
      const size_t bo_ = (size_t)(col0 + nt * 16 + m) * D + ko + hi * 8;
      bf16x8 bhf = *reinterpret_cast<const bf16x8*>(wh + bo_);
      acc[nt] = MFMA16(ah, bhf, acc[nt]);
      if (full) {
        bf16x8 blf = *reinterpret_cast<const bf16x8*>(wl + bo_);
        acc[nt] = MFMA16(ah, blf, acc[nt]);
        acc[nt] = MFMA16(al, bhf, acc[nt]);
      }
    }
  }
  const int bb = t0 >> 11, lloc0 = t0 & (L - 1);
  #pragma unroll
  for (int nt = 0; nt < 8; ++nt) {
    const int col = col0 + nt * 16 + m;
    const int hh = col >> 6, d = col & 63;
    const float bv_ = ldf(bias, (size_t)col);
    if (z == 2) {
      ushort4 hv;
      hv.x = bfh(acc[nt][0] + bv_);
      hv.y = bfh(acc[nt][1] + bv_);
      hv.z = bfh(acc[nt][2] + bv_);
      hv.w = bfh(acc[nt][3] + bv_);
      const size_t o = ((size_t)(bb * H + hh) * HD + d) * L + lloc0 + 4 * hi;
      *reinterpret_cast<ushort4*>(vth + o) = hv;
    } else {
      ushort_t* oh = z == 0 ? qh : kh;
      ushort_t* ol = z == 0 ? ql : kl;
      #pragma unroll
      for (int r = 0; r < 4; ++r) {
        const int tok = lloc0 + 4 * hi + r;
        float v = acc[nt][r] + bv_;
        const size_t o = ((size_t)(bb * H + hh) * L + tok) * HD + d;
        ushort_t hu = bfh(v);
        oh[o] = hu; ol[o] = bfh(v - bf2f(hu));
      }
    }
  }
}

// ---------------- Kernel 2: attention (barrier-free reg-direct MFMA) -----------
// 1024 blocks of 256 (XCD-swizzled). 4 fully independent waves per block; all
// K/V MFMA fragments are 16B-contiguous global loads (L2-resident, L1 shares
// across waves) -> NO __syncthreads anywhere. Only LDS use: per-wave 2 KB P
// transpose slice, ordered by in-wave lgkmcnt fences.
// Pass 1 is hi-only QK (errors in m cancel exactly; error in l ~0.003 rel).
// Pass 2: 3-product QK (accurate scores), 1-product PV.
template<typename T>
__global__ __launch_bounds__(256)
void attn_kernel(const int* __restrict__ flag,
                 const ushort_t* __restrict__ Qh_g, const ushort_t* __restrict__ Ql_g,
                 const ushort_t* __restrict__ Kh_g, const ushort_t* __restrict__ Kl_g,
                 const ushort_t* __restrict__ Vth_g,
                 const T* __restrict__ lsp, const T* __restrict__ gsp,
                 T* __restrict__ attn_l, T* __restrict__ attn_g,
                 ushort_t* __restrict__ AOh) {
  if (*flag != IsF32<T>::value) return;
  const int bid = blockIdx.x;
  const int xcd = bid & 7, slot = bid >> 3;       // 128 slots
  const int bhg = xcd + 8 * (slot >> 5);          // 0..31 (b,h)
  const int strip_raw = slot & 31;
  const int bb = bhg >> 4, h = bhg & 15;
  const bool is_local = h < LH;
  const int strip = is_local ? (31 - strip_raw) : strip_raw;  // long strips first
  const int q0 = strip * 64;
  const int ln = threadIdx.x & 63, w = threadIdx.x >> 6;
  const int m = ln & 15, hi = ln >> 4;

  const float cscale =
      (is_local ? ldf(lsp, (size_t)0) : ldf(gsp, (size_t)0)) * 0.125f;
  const size_t bh_off = ((size_t)bb * H + h) * L * HD;
  const ushort_t* Qhb = Qh_g + bh_off;
  const ushort_t* Qlb = Ql_g + bh_off;
  const ushort_t* Khb = Kh_g + bh_off;
  const ushort_t* Klb = Kl_g + bh_off;
  const ushort_t* Vhb = Vth_g + bh_off;   // [HD][L] per (b,h)

  __shared__ ushort_t Ps[4096];           // 8 KB; wave w owns rows 16w..16w+15

  // Q fragments (B-operand; persist whole kernel)
  bf16x8 qfh[2], qfl[2];
  {
    const size_t qb = (size_t)(q0 + 16 * w + m) * HD + hi * 8;
    qfh[0] = *reinterpret_cast<const bf16x8*>(Qhb + qb);
    qfh[1] = *reinterpret_cast<const bf16x8*>(Qhb + qb + 32);
    qfl[0] = *reinterpret_cast<const bf16x8*>(Qlb + qb);
    qfl[1] = *reinterpret_cast<const bf16x8*>(Qlb + qb + 32);
  }

  float m_ = NEG_INF, l_ = 0.f;
  const int nkt = is_local ? (strip + 1) : (L / 64);
  T* aout = is_local ? attn_l : attn_g;
  const size_t arow0 =
      ((size_t)(bb * LH + (is_local ? h : h - LH)) * L + q0) * L;

  // ---------------- pass 1: row max / sum (hi-only QK: 8 MFMA/tile) -----------
  #pragma unroll 2
  for (int kt = 0; kt < nkt; ++kt) {
    const ushort_t* kb = Khb + (size_t)(kt * 64) * HD;
    bf16x8 kh0[4], kh1[4];
    #pragma unroll
    for (int nt = 0; nt < 4; ++nt) {
      const size_t ro = (size_t)(nt * 16 + m) * HD + hi * 8;
      kh0[nt] = *reinterpret_cast<const bf16x8*>(kb + ro);
      kh1[nt] = *reinterpret_cast<const bf16x8*>(kb + ro + 32);
    }
    f32x4 s[4] = {};
    __builtin_amdgcn_s_setprio(1);
    #pragma unroll
    for (int nt = 0; nt < 4; ++nt) {
      s[nt] = MFMA16(kh0[nt], qfh[0], s[nt]);
      s[nt] = MFMA16(kh1[nt], qfh[1], s[nt]);
    }
    __builtin_amdgcn_s_setprio(0);

    const bool dg = is_local && (kt == strip);
    #pragma unroll
    for (int nt = 0; nt < 4; ++nt)
      #pragma unroll
      for (int r = 0; r < 4; ++r) {
        float v = s[nt][r] * cscale;
        if (dg && (nt * 16 + 4 * hi + r > 16 * w + m)) v = NEG_INF;
        s[nt][r] = v;
      }

    float tm = NEG_INF;
    #pragma unroll
    for (int nt = 0; nt < 4; ++nt)
      #pragma unroll
      for (int r = 0; r < 4; ++r) tm = fmaxf(tm, s[nt][r]);
    tm = fmaxf(tm, __shfl_xor(tm, 16, 64));
    tm = fmaxf(tm, __shfl_xor(tm, 32, 64));
    const float mn = fmaxf(m_, tm);
    float sum = 0.f;
    #pragma unroll
    for (int nt = 0; nt < 4; ++nt)
      #pragma unroll
      for (int r = 0; r < 4; ++r) sum += __expf(s[nt][r] - mn);
    sum += __shfl_xor(sum, 16, 64);
    sum += __shfl_xor(sum, 32, 64);
    l_ = l_ * __expf(m_ - mn) + sum;
    m_ = mn;
  }

  const float invl = 1.0f / l_;
  f32x4 o_[4] = {};

  // ---------------- pass 2: 3-product QK, probs, 1-product PV -----------------
  for (int kt = 0; kt < nkt; ++kt) {
    const ushort_t* kb  = Khb + (size_t)(kt * 64) * HD;
    const ushort_t* kbl = Klb + (size_t)(kt * 64) * HD;
    bf16x8 kh0[4], kh1[4];
    #pragma unroll
    for (int nt = 0; nt < 4; ++nt) {
      const size_t ro = (size_t)(nt * 16 + m) * HD + hi * 8;
      kh0[nt] = *reinterpret_cast<const bf16x8*>(kb + ro);
      kh1[nt] = *reinterpret_cast<const bf16x8*>(kb + ro + 32);
    }
    f32x4 s[4] = {};
    __builtin_amdgcn_s_setprio(1);
    #pragma unroll
    for (int nt = 0; nt < 4; ++nt) {
      s[nt] = MFMA16(kh0[nt], qfh[0], s[nt]);
      s[nt] = MFMA16(kh1[nt], qfh[1], s[nt]);
    }
    #pragma unroll
    for (int nt = 0; nt < 4; ++nt) {
      const size_t ro = (size_t)(nt * 16 + m) * HD + hi * 8;
      bf16x8 kl0 = *reinterpret_cast<const bf16x8*>(kbl + ro);
      bf16x8 kl1 = *reinterpret_cast<const bf16x8*>(kbl + ro + 32);
      s[nt] = MFMA16(kl0, qfh[0], s[nt]);
      s[nt] = MFMA16(kl1, qfh[1], s[nt]);
      s[nt] = MFMA16(kh0[nt], qfl[0], s[nt]);
      s[nt] = MFMA16(kh1[nt], qfl[1], s[nt]);
    }
    __builtin_amdgcn_s_setprio(0);

    const bool dg = is_local && (kt == strip);
    #pragma unroll
    for (int nt = 0; nt < 4; ++nt) {
      float v0 = s[nt][0] * cscale, v1 = s[nt][1] * cscale;
      float v2 = s[nt][2] * cscale, v3 = s[nt][3] * cscale;
      if (dg) {
        const int kbq = nt * 16 + 4 * hi, qq = 16 * w + m;
        if (kbq + 0 > qq) v0 = NEG_INF;
        if (kbq + 1 > qq) v1 = NEG_INF;
        if (kbq + 2 > qq) v2 = NEG_INF;
        if (kbq + 3 > qq) v3 = NEG_INF;
      }
      ushort4 pk;
      pk.x = bfh(__expf(v0 - m_) * invl);
      pk.y = bfh(__expf(v1 - m_) * invl);
      pk.z = bfh(__expf(v2 - m_) * invl);
      pk.w = bfh(__expf(v3 - m_) * invl);
      *reinterpret_cast<ushort4*>(&Ps[swzc(16 * w + m, nt * 16 + 4 * hi)]) = pk;
    }
    LGKM0_FENCE();   // wave-local: P writes visible to this wave's reads

    bf16x8 pf0 = *reinterpret_cast<const bf16x8*>(&Ps[swz(16 * w + m, hi)]);
    bf16x8 pf1 = *reinterpret_cast<const bf16x8*>(&Ps[swz(16 * w + m, 4 + hi)]);
    __builtin_amdgcn_s_setprio(1);
    #pragma unroll
    for (int dt = 0; dt < 4; ++dt) {
      const size_t vo = (size_t)(dt * 16 + m) * L + kt * 64 + hi * 8;
      bf16x8 vf0 = *reinterpret_cast<const bf16x8*>(Vhb + vo);
      bf16x8 vf1 = *reinterpret_cast<const bf16x8*>(Vhb + vo + 32);
      o_[dt] = MFMA16(pf0, vf0, o_[dt]);
      o_[dt] = MFMA16(pf1, vf1, o_[dt]);
    }
    __builtin_amdgcn_s_setprio(0);

    // coalesced prob write: wave reads its own 16 Ps rows, 128-B global segments
    {
      const int pr = 16 * w + (ln >> 2);
      const int cs = (ln & 3) * 2;
      us8 v0 = *reinterpret_cast<const us8*>(&Ps[swz(pr, cs)]);
      us8 v1 = *reinterpret_cast<const us8*>(&Ps[swz(pr, cs + 1)]);
      const size_t gi = arow0 + (size_t)pr * L + (size_t)(kt * 64 + (ln & 3) * 16);
      if constexpr (IsF32<T>::value) {
        float* dst = (float*)aout + gi;
        *reinterpret_cast<float4*>(dst + 0) =
            make_float4(bf2f(v0[0]), bf2f(v0[1]), bf2f(v0[2]), bf2f(v0[3]));
        *reinterpret_cast<float4*>(dst + 4) =
            make_float4(bf2f(v0[4]), bf2f(v0[5]), bf2f(v0[6]), bf2f(v0[7]));
        *reinterpret_cast<float4*>(dst + 8) =
            make_float4(bf2f(v1[0]), bf2f(v1[1]), bf2f(v1[2]), bf2f(v1[3]));
        *reinterpret_cast<float4*>(dst + 12) =
            make_float4(bf2f(v1[4]), bf2f(v1[5]), bf2f(v1[6]), bf2f(v1[7]));
      } else {
        bf16* dst = (bf16*)aout + gi;
        *reinterpret_cast<uint4*>(dst + 0) = *reinterpret_cast<const uint4*>(&v0);
        *reinterpret_cast<uint4*>(dst + 8) = *reinterpret_cast<const uint4*>(&v1);
      }
    }
    LGKM0_FENCE();   // all Ps reads done before next tile overwrites
  }

  // fully-masked region of causal heads: probs exactly 0 (coalesced)
  if (is_local) {
    const int pr = 16 * w + (ln >> 2);
    const size_t rbase = arow0 + (size_t)pr * L;
    for (int c = nkt * 64 + (ln & 3) * 16; c < L; c += 64) {
      if constexpr (IsF32<T>::value) {
        float* dst = (float*)aout + rbase + c;
        const float4 z4 = make_float4(0.f, 0.f, 0.f, 0.f);
        *reinterpret_cast<float4*>(dst + 0) = z4;
        *reinterpret_cast<float4*>(dst + 4) = z4;
        *reinterpret_cast<float4*>(dst + 8) = z4;
        *reinterpret_cast<float4*>(dst + 12) = z4;
      } else {
        bf16* dst = (bf16*)aout + rbase + c;
        const uint4 z4 = make_uint4(0u, 0u, 0u, 0u);
        *reinterpret_cast<uint4*>(dst + 0) = z4;
        *reinterpret_cast<uint4*>(dst + 8) = z4;
      }
    }
  }

  // AO [B,L,D] as bf16 hi plane (feeds 1-product out_proj)
  #pragma unroll
  for (int dt = 0; dt < 4; ++dt)
    #pragma unroll
    for (int r = 0; r < 4; ++r)
      AOh[((size_t)bb * L + q0 + 16 * w + 4 * hi + r) * D + h * HD + dt * 16 + m] =
          bfh(o_[dt][r]);
}

// ---------------- Kernel 3: output projection (1-product MFMA GEMM) ------------
template<typename T>
__global__ __launch_bounds__(256)
void out_proj_kernel(const int* __restrict__ flag,
                     const ushort_t* __restrict__ ah_,
                     const ushort_t* __restrict__ wh,
                     const T* __restrict__ bo, T* __restrict__ out) {
  if (*flag != IsF32<T>::value) return;
  const int bid = blockIdx.x;                      // 512 blocks
  const int xcd = bid & 7, slot = bid >> 3;        // 64 slots
  const int col0 = xcd * 128;
  const int lane = threadIdx.x & 63, w = threadIdx.x >> 6;
  const int t0 = slot * 64 + w * 16;
  const int m = lane & 15, hi = lane >> 4;

  f32x4 acc[8] = {};
  const size_t arow = (size_t)(t0 + m) * D + hi * 8;
  for (int kc = 0; kc < 32; ++kc) {
    const int ko = kc * 32;
    bf16x8 ah = *reinterpret_cast<const bf16x8*>(ah_ + arow + ko);
    #pragma unroll
    for (int nt = 0; nt < 8; ++nt) {
      const size_t bo_ = (size_t)(col0 + nt * 16 + m) * D + ko + hi * 8;
      bf16x8 bhf = *reinterpret_cast<const bf16x8*>(wh + bo_);
      acc[nt] = MFMA16(ah, bhf, acc[nt]);
    }
  }
  #pragma unroll
  for (int nt = 0; nt < 8; ++nt) {
    const int col = col0 + nt * 16 + m;
    const float bv_ = ldf(bo, (size_t)col);
    #pragma unroll
    for (int r = 0; r < 4; ++r) {
      const int tok = t0 + 4 * hi + r;
      stf(out, (size_t)tok * D + col, acc[nt][r] + bv_);
    }
  }
}

template<typename T>
static void launch_path(void* const* d_in, void* d_out, void* d_ws, hipStream_t stream) {
  const int want = IsF32<T>::value;
  const int* flag = (const int*)d_ws;
  ushort_t* Qh  = (ushort_t*)((char*)d_ws + 256);
  ushort_t* Ql  = Qh + 4194304;
  ushort_t* Kh  = Ql + 4194304;
  ushort_t* Kl  = Kh + 4194304;
  ushort_t* Vth = Kl + 4194304;
  ushort_t* AOh = Vth + 4194304;
  ushort_t* Woth = AOh + 4194304;         // dedicated 2 MB (survives attn)
  // total ws use ≈ 50.6 MB

  const T* x  = (const T*)d_in[0];
  const T* Wq = (const T*)d_in[1];
  const T* bq = (const T*)d_in[2];
  const T* Wk = (const T*)d_in[3];
  const T* bk = (const T*)d_in[4];
  const T* Wv = (const T*)d_in[5];
  const T* bv = (const T*)d_in[6];
  const T* Wo = (const T*)d_in[7];
  const T* bo = (const T*)d_in[8];
  const T* ls = (const T*)d_in[9];
  const T* gs = (const T*)d_in[10];

  T* out0   = (T*)d_out;
  T* attn_l = out0 + (size_t)B * L * D;
  T* attn_g = attn_l + (size_t)B * LH * L * L;
  // scratch inside the not-yet-written attn_g output region (dead after proj)
  ushort_t* xh  = (ushort_t*)attn_g;
  ushort_t* xl  = xh + 4194304;
  ushort_t* Wt3 = xh + 8388608;           // 3 mats x (h,l) planes

  constexpr int NSA = IsF32<T>::value ? 2 : 1;

  if constexpr (IsF32<T>::value)
    split_f32_kernel<<<1024, 256, 0, stream>>>(flag, want, (const float*)x, xh, xl, 1048576);
  transW_kernel<T><<<dim3(16, 16, 4), 256, 0, stream>>>(
      flag, Wq, Wk, Wv, Wo, Wt3, Woth, 2);
  const ushort_t* xA = IsF32<T>::value ? xh : (const ushort_t*)x;
  proj_kernel<T, NSA><<<1536, 256, 0, stream>>>(
      flag, xA, xl, Wt3, bq, bk, bv, Qh, Ql, Kh, Kl, Vth);
  attn_kernel<T><<<1024, 256, 0, stream>>>(
      flag, Qh, Ql, Kh, Kl, Vth, ls, gs, attn_l, attn_g, AOh);
  out_proj_kernel<T><<<512, 256, 0, stream>>>(flag, AOh, Woth, bo, out0);
}

extern "C" void kernel_launch(void* const* d_in, const int* in_sizes, int n_in,
                              void* d_out, int out_size, void* d_ws, size_t ws_size,
                              hipStream_t stream) {
  int* flag = (int*)d_ws;
  detect_dtype_kernel<<<1, 64, 0, stream>>>((const unsigned short*)d_in[0], flag);
  launch_path<float>(d_in, d_out, d_ws, stream);
  launch_path<bf16>(d_in, d_out, d_ws, stream);
}

// Round 6
// 972.038 us; speedup vs baseline: 1.5206x; 1.5206x over previous
//
#include <hip/hip_runtime.h>
#include <hip/hip_bf16.h>

#define B 2
#define L 2048
#define D 1024
#define H 16
#define HD 64
#define LH 8
#define NEG_INF -1e30f

typedef __hip_bfloat16 bf16;
typedef unsigned short ushort_t;
typedef short bf16x8 __attribute__((ext_vector_type(8)));
typedef unsigned short us8 __attribute__((ext_vector_type(8)));
typedef float f32x4 __attribute__((ext_vector_type(4)));

#define MFMA16(a, b, c) __builtin_amdgcn_mfma_f32_16x16x32_bf16((a), (b), (c), 0, 0, 0)

#if defined(__has_builtin)
#if __has_builtin(__builtin_amdgcn_global_load_lds)
#define HAVE_GLOAD_LDS 1
#endif
#endif

template<typename T> struct IsF32;
template<> struct IsF32<float> { static constexpr int value = 1; };
template<> struct IsF32<bf16>  { static constexpr int value = 0; };

__device__ __forceinline__ float ldf(const float* p, size_t i) { return p[i]; }
__device__ __forceinline__ float ldf(const bf16* p, size_t i) { return __bfloat162float(p[i]); }

__device__ __forceinline__ float4 ld4(const float* p, size_t i) {
  return *reinterpret_cast<const float4*>(p + i);
}
__device__ __forceinline__ float4 ld4(const bf16* p, size_t i) {
  ushort4 u = *reinterpret_cast<const ushort4*>(p + i);
  float4 f;
  f.x = __uint_as_float(((unsigned)u.x) << 16);
  f.y = __uint_as_float(((unsigned)u.y) << 16);
  f.z = __uint_as_float(((unsigned)u.z) << 16);
  f.w = __uint_as_float(((unsigned)u.w) << 16);
  return f;
}
__device__ __forceinline__ ushort_t bfh(float v) {
  bf16 h = __float2bfloat16(v);
  return *reinterpret_cast<ushort_t*>(&h);
}
__device__ __forceinline__ float bf2f(ushort_t u) {
  return __uint_as_float(((unsigned)u) << 16);
}
__device__ __forceinline__ void stf(float* p, size_t i, float v) { p[i] = v; }
__device__ __forceinline__ void stf(bf16* p, size_t i, float v) { p[i] = __float2bfloat16(v); }
__device__ __forceinline__ void st4(float* p, size_t i, float4 v) {
  *reinterpret_cast<float4*>(p + i) = v;
}

// XOR-swizzled LDS addressing: 64-ushort (128 B) rows, 8 slots of 8 ushorts (16 B).
// slot' = slot ^ (row & 7)  -> 16B-aligned ds_*_b128, bank-conflict-reduced.
__device__ __forceinline__ int swz(int row, int slot) {
  return row * 64 + (((slot ^ (row & 7)) & 7) << 3);
}
__device__ __forceinline__ int swzc(int row, int c) {   // per-ushort column c
  return row * 64 + (((((c >> 3) ^ row) & 7) << 3) | (c & 7));
}

#if defined(HAVE_GLOAD_LDS)
__device__ __forceinline__ void gload_lds16(const ushort_t* src, ushort_t* dst) {
  __builtin_amdgcn_global_load_lds(
      (const __attribute__((address_space(1))) unsigned int*)src,
      (__attribute__((address_space(3))) unsigned int*)dst, 16, 0, 0);
}
#endif

// Stage a 64x64 ushort tile (16 rows per wave) into swizzled LDS. LDS dest is
// linear; the XOR swizzle is applied to the GLOBAL source slot (rule #21).
__device__ __forceinline__ void stage64(const ushort_t* g, size_t gstride,
                                        ushort_t* lds, int w, int ln) {
  #pragma unroll
  for (int c = 0; c < 2; ++c) {
    const int row = 16 * w + 8 * c + (ln >> 3);
    const int slot = ((ln & 7) ^ row) & 7;
    const ushort_t* src = g + (size_t)row * gstride + slot * 8;
#if defined(HAVE_GLOAD_LDS)
    gload_lds16(src, lds + (size_t)(16 * w + 8 * c) * 64);
#else
    *reinterpret_cast<uint4*>(&lds[row * 64 + (ln & 7) * 8]) =
        *reinterpret_cast<const uint4*>(src);
#endif
  }
}

// Stage a 128-row x 64-ushort tile (32 rows per wave), global row stride 1024.
__device__ __forceinline__ void stage128(const ushort_t* g, ushort_t* lds,
                                         int w, int ln) {
  #pragma unroll
  for (int c = 0; c < 4; ++c) {
    const int row = 32 * w + 8 * c + (ln >> 3);
    const int slot = ((ln & 7) ^ row) & 7;
    const ushort_t* src = g + (size_t)row * 1024 + slot * 8;
#if defined(HAVE_GLOAD_LDS)
    gload_lds16(src, lds + (size_t)(32 * w + 8 * c) * 64);
#else
    *reinterpret_cast<uint4*>(&lds[row * 64 + (ln & 7) * 8]) =
        *reinterpret_cast<const uint4*>(src);
#endif
  }
}

// Runtime dtype detection: fp32 data reinterpreted as u16 pairs shows large
// "exponent" fields in low halves with prob ~1/3; bf16 N(0,1) never does.
__global__ void detect_dtype_kernel(const unsigned short* __restrict__ x,
                                    int* __restrict__ flag) {
  int bad = 0;
  for (int i = threadIdx.x; i < 1024; i += 64) {
    if (((x[i] >> 7) & 0xFF) >= 170) bad = 1;
  }
  unsigned long long m = __ballot(bad);
  if (threadIdx.x == 0) *flag = (m != 0ULL) ? 1 : 0;
}

// ---------------- prep: split fp32 array into bf16 hi/lo planes ----------------
__global__ __launch_bounds__(256)
void split_f32_kernel(const int* __restrict__ flag, int want,
                      const float* __restrict__ in,
                      ushort_t* __restrict__ hp, ushort_t* __restrict__ lp, int n4) {
  if (*flag != want) return;
  int i = blockIdx.x * 256 + threadIdx.x;
  const int stride = gridDim.x * 256;
  for (; i < n4; i += stride) {
    float4 v = *reinterpret_cast<const float4*>(in + 4 * (size_t)i);
    ushort4 h, l;
    h.x = bfh(v.x); l.x = bfh(v.x - bf2f(h.x));
    h.y = bfh(v.y); l.y = bfh(v.y - bf2f(h.y));
    h.z = bfh(v.z); l.z = bfh(v.z - bf2f(h.z));
    h.w = bfh(v.w); l.w = bfh(v.w - bf2f(h.w));
    *reinterpret_cast<ushort4*>(hp + 4 * (size_t)i) = h;
    *reinterpret_cast<ushort4*>(lp + 4 * (size_t)i) = l;
  }
}

// ---------------- prep: transpose W [K][N] -> Wt [N][K], split to bf16 hi/lo ----
// grid (16,16,4): z=0..2 -> Wq/Wk/Wv into base (+lo for z<lo_upto); z=3 -> Wo
// hi-only into baseWo.
template<typename T>
__global__ __launch_bounds__(256)
void transW_kernel(const int* __restrict__ flag,
                   const T* __restrict__ W0, const T* __restrict__ W1,
                   const T* __restrict__ W2, const T* __restrict__ W3,
                   ushort_t* __restrict__ base, ushort_t* __restrict__ baseWo,
                   int lo_upto) {
  if (*flag != IsF32<T>::value) return;
  const int z = blockIdx.z;
  const T* W = z == 0 ? W0 : (z == 1 ? W1 : (z == 2 ? W2 : W3));
  ushort_t* hp = (z < 3) ? (base + (size_t)z * 2097152) : baseWo;
  ushort_t* lp = hp + 1048576;
  const bool wl_ = IsF32<T>::value && (z < lo_upto);
  __shared__ float ts[64][69];
  const int k0 = blockIdx.x * 64, n0 = blockIdx.y * 64;
  const int t = threadIdx.x;
  #pragma unroll
  for (int p = 0; p < 4; ++p) {
    int r = p * 16 + (t >> 4);
    int c = (t & 15) * 4;
    float4 v = ld4(W, (size_t)(k0 + r) * D + n0 + c);
    ts[r][c] = v.x; ts[r][c + 1] = v.y; ts[r][c + 2] = v.z; ts[r][c + 3] = v.w;
  }
  __syncthreads();
  #pragma unroll
  for (int p = 0; p < 4; ++p) {
    int n = p * 16 + (t >> 4);
    int k4 = (t & 15) * 4;
    ushort4 h, l;
    float a0 = ts[k4][n], a1 = ts[k4 + 1][n], a2 = ts[k4 + 2][n], a3 = ts[k4 + 3][n];
    h.x = bfh(a0); l.x = bfh(a0 - bf2f(h.x));
    h.y = bfh(a1); l.y = bfh(a1 - bf2f(h.y));
    h.z = bfh(a2); l.z = bfh(a2 - bf2f(h.z));
    h.w = bfh(a3); l.w = bfh(a3 - bf2f(h.w));
    size_t o = (size_t)(n0 + n) * D + k0 + k4;
    *reinterpret_cast<ushort4*>(hp + o) = h;
    if (wl_) *reinterpret_cast<ushort4*>(lp + o) = l;
  }
}

// ---------------- Kernel 1/3: LDS-staged MFMA GEMM (m97-style) -----------------
// 128x128 tile, BK=64, 4 waves in 2x2 grid (64x64 each, 4x4 fragments).
// global_load_lds staging (inverse-swizzled source), ds_read_b128 fragments,
// 2 barriers per K-step. z=0 (Q) / z=1 (K): 3-product on fp32 path, hi+lo out.
// z=2 (V): 1-product, transposed hi out. z=3 (out-proj): 1-product, T out.
template<typename T, int NSA>
__global__ __launch_bounds__(256, 2)
void gemm_kernel(const int* __restrict__ flag,
                 const ushort_t* __restrict__ xA, const ushort_t* __restrict__ xAl,
                 const ushort_t* __restrict__ aoh,
                 const ushort_t* __restrict__ wbase, const ushort_t* __restrict__ woT,
                 const T* __restrict__ bq, const T* __restrict__ bk,
                 const T* __restrict__ bv, const T* __restrict__ bo,
                 ushort_t* __restrict__ qh, ushort_t* __restrict__ ql,
                 ushort_t* __restrict__ kh, ushort_t* __restrict__ kl,
                 ushort_t* __restrict__ vth, T* __restrict__ out0, int zbase) {
  if (*flag != IsF32<T>::value) return;
  // XCD-chunked bijective swizzle (gridDim.x divisible by 8)
  const int cpx = gridDim.x >> 3;
  const int swzid = ((int)blockIdx.x & 7) * cpx + ((int)blockIdx.x >> 3);
  const int mtile = swzid & 31;
  const int rest = swzid >> 5;
  const int ntile = rest & 7;
  const int z = zbase + (rest >> 3);
  const int m0 = mtile * 128, n0 = ntile * 128;

  const bool isOut = (z == 3);
  const ushort_t* Ah = isOut ? aoh : xA;
  const ushort_t* wh = isOut ? woT : (wbase + (size_t)z * 2097152);
  const ushort_t* wl = wh + 1048576;
  const bool full = (NSA == 2) && (z < 2);

  __shared__ ushort_t AsH[8192], AsL[8192], BsH[8192], BsL[8192];   // 64 KB

  const int ln = threadIdx.x & 63, w = threadIdx.x >> 6;
  const int m = ln & 15, hi = ln >> 4;
  const int wr = w >> 1, wc = w & 1;

  f32x4 acc[4][4] = {};

  for (int k0 = 0; k0 < 1024; k0 += 64) {
    stage128(Ah + (size_t)m0 * 1024 + k0, AsH, w, ln);
    stage128(wh + (size_t)n0 * 1024 + k0, BsH, w, ln);
    if (full) {
      stage128(xAl + (size_t)m0 * 1024 + k0, AsL, w, ln);
      stage128(wl + (size_t)n0 * 1024 + k0, BsL, w, ln);
    }
    __syncthreads();
    #pragma unroll
    for (int kc = 0; kc < 2; ++kc) {
      bf16x8 a_h[4], b_h[4];
      #pragma unroll
      for (int f = 0; f < 4; ++f) {
        a_h[f] = *reinterpret_cast<const bf16x8*>(&AsH[swz(wr * 64 + f * 16 + m, kc * 4 + hi)]);
        b_h[f] = *reinterpret_cast<const bf16x8*>(&BsH[swz(wc * 64 + f * 16 + m, kc * 4 + hi)]);
      }
      #pragma unroll
      for (int fr = 0; fr < 4; ++fr)
        #pragma unroll
        for (int fc = 0; fc < 4; ++fc)
          acc[fr][fc] = MFMA16(a_h[fr], b_h[fc], acc[fr][fc]);
      if (full) {
        bf16x8 a_l[4], b_l[4];
        #pragma unroll
        for (int f = 0; f < 4; ++f) {
          a_l[f] = *reinterpret_cast<const bf16x8*>(&AsL[swz(wr * 64 + f * 16 + m, kc * 4 + hi)]);
          b_l[f] = *reinterpret_cast<const bf16x8*>(&BsL[swz(wc * 64 + f * 16 + m, kc * 4 + hi)]);
        }
        #pragma unroll
        for (int fr = 0; fr < 4; ++fr)
          #pragma unroll
          for (int fc = 0; fc < 4; ++fc) {
            acc[fr][fc] = MFMA16(a_h[fr], b_l[fc], acc[fr][fc]);
            acc[fr][fc] = MFMA16(a_l[fr], b_h[fc], acc[fr][fc]);
          }
      }
    }
    __syncthreads();
  }

  // ---------------- epilogue ----------------
  #pragma unroll
  for (int fc = 0; fc < 4; ++fc) {
    const int col = n0 + wc * 64 + fc * 16 + m;
    if (isOut) {
      const float bv_ = ldf(bo, (size_t)col);
      #pragma unroll
      for (int fr = 0; fr < 4; ++fr)
        #pragma unroll
        for (int r = 0; r < 4; ++r) {
          const int tok = m0 + wr * 64 + fr * 16 + 4 * hi + r;
          stf(out0, (size_t)tok * D + col, acc[fr][fc][r] + bv_);
        }
    } else if (z == 2) {
      const int hh = col >> 6, d = col & 63;
      const float bv_ = ldf(bv, (size_t)col);
      #pragma unroll
      for (int fr = 0; fr < 4; ++fr) {
        const int tok0 = m0 + wr * 64 + fr * 16 + 4 * hi;
        const int bb = tok0 >> 11, ll = tok0 & (L - 1);
        ushort4 hv;
        hv.x = bfh(acc[fr][fc][0] + bv_);
        hv.y = bfh(acc[fr][fc][1] + bv_);
        hv.z = bfh(acc[fr][fc][2] + bv_);
        hv.w = bfh(acc[fr][fc][3] + bv_);
        *reinterpret_cast<ushort4*>(
            &vth[((size_t)(bb * H + hh) * HD + d) * L + ll]) = hv;
      }
    } else {
      const int hh = col >> 6, d = col & 63;
      const float bv_ = ldf(z == 0 ? bq : bk, (size_t)col);
      ushort_t* oh = z == 0 ? qh : kh;
      ushort_t* ol = z == 0 ? ql : kl;
      #pragma unroll
      for (int fr = 0; fr < 4; ++fr)
        #pragma unroll
        for (int r = 0; r < 4; ++r) {
          const int tok = m0 + wr * 64 + fr * 16 + 4 * hi + r;
          const int bb = tok >> 11, ll = tok & (L - 1);
          const float v = acc[fr][fc][r] + bv_;
          const size_t o = ((size_t)(bb * H + hh) * L + ll) * HD + d;
          const ushort_t hu = bfh(v);
          oh[o] = hu; ol[o] = bfh(v - bf2f(hu));
        }
    }
  }
}

// ---------------- Kernel 2: attention (Round-3 structure, 400 µs measured) -----
// 1024 blocks of 256 (XCD-swizzled). Block = 64 q-rows (4 waves x 16, swapped
// layout: lane owns one q-row). K/V staged in swizzled LDS via global_load_lds,
// 2 barriers per tile. Pass 1 hi-only QK (m-errors cancel exactly in exp(s-m)/l);
// pass 2: 3-product QK, 1-product PV, coalesced prob writes from LDS.
template<typename T>
__global__ __launch_bounds__(256)
void attn_kernel(const int* __restrict__ flag,
                 const ushort_t* __restrict__ Qh_g, const ushort_t* __restrict__ Ql_g,
                 const ushort_t* __restrict__ Kh_g, const ushort_t* __restrict__ Kl_g,
                 const ushort_t* __restrict__ Vth_g,
                 const T* __restrict__ lsp, const T* __restrict__ gsp,
                 T* __restrict__ attn_l, T* __restrict__ attn_g,
                 ushort_t* __restrict__ AOh) {
  if (*flag != IsF32<T>::value) return;
  const int bid = blockIdx.x;
  const int xcd = bid & 7, slot = bid >> 3;       // 128 slots
  const int bhg = xcd + 8 * (slot >> 5);          // 0..31 (b,h)
  const int strip_raw = slot & 31;
  const int bb = bhg >> 4, h = bhg & 15;
  const bool is_local = h < LH;
  const int strip = is_local ? (31 - strip_raw) : strip_raw;  // long strips first
  const int q0 = strip * 64;
  const int ln = threadIdx.x & 63, w = threadIdx.x >> 6;
  const int m = ln & 15, hi = ln >> 4;

  const float cscale =
      (is_local ? ldf(lsp, (size_t)0) : ldf(gsp, (size_t)0)) * 0.125f;
  const size_t bh_off = ((size_t)bb * H + h) * L * HD;
  const ushort_t* Qhb = Qh_g + bh_off;
  const ushort_t* Qlb = Ql_g + bh_off;
  const ushort_t* Khb = Kh_g + bh_off;
  const ushort_t* Klb = Kl_g + bh_off;
  const ushort_t* Vhb = Vth_g + bh_off;   // [HD][L] per (b,h)

  __shared__ ushort_t KsH[4096], KsL[4096], VsH[4096], Ps[4096];   // 32 KB

  // Q fragments (B-operand; persist whole kernel)
  bf16x8 qfh[2], qfl[2];
  {
    const size_t qb = (size_t)(q0 + 16 * w + m) * HD + hi * 8;
    qfh[0] = *reinterpret_cast<const bf16x8*>(Qhb + qb);
    qfh[1] = *reinterpret_cast<const bf16x8*>(Qhb + qb + 32);
    qfl[0] = *reinterpret_cast<const bf16x8*>(Qlb + qb);
    qfl[1] = *reinterpret_cast<const bf16x8*>(Qlb + qb + 32);
  }

  float m_ = NEG_INF, l_ = 0.f;
  const int nkt = is_local ? (strip + 1) : (L / 64);
  T* aout = is_local ? attn_l : attn_g;
  const size_t arow0 =
      ((size_t)(bb * LH + (is_local ? h : h - LH)) * L + q0) * L;

  // ---------------- pass 1: row max / sum (hi-only: 8 MFMA/tile) --------------
  for (int kt = 0; kt < nkt; ++kt) {
    stage64(Khb + (size_t)(kt * 64) * HD, HD, KsH, w, ln);
    __syncthreads();

    f32x4 s[4] = {};
    __builtin_amdgcn_s_setprio(1);
    #pragma unroll
    for (int nt = 0; nt < 4; ++nt) {
      #pragma unroll
      for (int kc = 0; kc < 2; ++kc) {
        bf16x8 kbh = *reinterpret_cast<const bf16x8*>(&KsH[swz(nt * 16 + m, kc * 4 + hi)]);
        s[nt] = MFMA16(kbh, qfh[kc], s[nt]);
      }
    }
    __builtin_amdgcn_s_setprio(0);

    const bool dg = is_local && (kt == strip);
    #pragma unroll
    for (int nt = 0; nt < 4; ++nt)
      #pragma unroll
      for (int r = 0; r < 4; ++r) {
        float v = s[nt][r] * cscale;
        if (dg && (nt * 16 + 4 * hi + r > 16 * w + m)) v = NEG_INF;
        s[nt][r] = v;
      }

    float tm = NEG_INF;
    #pragma unroll
    for (int nt = 0; nt < 4; ++nt)
      #pragma unroll
      for (int r = 0; r < 4; ++r) tm = fmaxf(tm, s[nt][r]);
    tm = fmaxf(tm, __shfl_xor(tm, 16, 64));
    tm = fmaxf(tm, __shfl_xor(tm, 32, 64));
    const float mn = fmaxf(m_, tm);
    float sum = 0.f;
    #pragma unroll
    for (int nt = 0; nt < 4; ++nt)
      #pragma unroll
      for (int r = 0; r < 4; ++r) sum += __expf(s[nt][r] - mn);
    sum += __shfl_xor(sum, 16, 64);
    sum += __shfl_xor(sum, 32, 64);
    l_ = l_ * __expf(m_ - mn) + sum;
    m_ = mn;
    __syncthreads();
  }

  const float invl = 1.0f / l_;
  f32x4 o_[4] = {};

  // ---------------- pass 2: 3-product QK, probs, 1-product PV -----------------
  for (int kt = 0; kt < nkt; ++kt) {
    stage64(Khb + (size_t)(kt * 64) * HD, HD, KsH, w, ln);
    stage64(Klb + (size_t)(kt * 64) * HD, HD, KsL, w, ln);
    stage64(Vhb + (size_t)(kt * 64), L, VsH, w, ln);
    __syncthreads();

    f32x4 s[4] = {};
    __builtin_amdgcn_s_setprio(1);
    #pragma unroll
    for (int nt = 0; nt < 4; ++nt) {
      #pragma unroll
      for (int kc = 0; kc < 2; ++kc) {
        bf16x8 kbh = *reinterpret_cast<const bf16x8*>(&KsH[swz(nt * 16 + m, kc * 4 + hi)]);
        bf16x8 kbl = *reinterpret_cast<const bf16x8*>(&KsL[swz(nt * 16 + m, kc * 4 + hi)]);
        s[nt] = MFMA16(kbh, qfh[kc], s[nt]);
        s[nt] = MFMA16(kbl, qfh[kc], s[nt]);
        s[nt] = MFMA16(kbh, qfl[kc], s[nt]);
      }
    }
    __builtin_amdgcn_s_setprio(0);

    const bool dg = is_local && (kt == strip);
    #pragma unroll
    for (int nt = 0; nt < 4; ++nt) {
      float v0 = s[nt][0] * cscale, v1 = s[nt][1] * cscale;
      float v2 = s[nt][2] * cscale, v3 = s[nt][3] * cscale;
      if (dg) {
        const int kbq = nt * 16 + 4 * hi, qq = 16 * w + m;
        if (kbq + 0 > qq) v0 = NEG_INF;
        if (kbq + 1 > qq) v1 = NEG_INF;
        if (kbq + 2 > qq) v2 = NEG_INF;
        if (kbq + 3 > qq) v3 = NEG_INF;
      }
      ushort4 pk;
      pk.x = bfh(__expf(v0 - m_) * invl);
      pk.y = bfh(__expf(v1 - m_) * invl);
      pk.z = bfh(__expf(v2 - m_) * invl);
      pk.w = bfh(__expf(v3 - m_) * invl);
      *reinterpret_cast<ushort4*>(&Ps[swzc(16 * w + m, nt * 16 + 4 * hi)]) = pk;
    }

    // PV (1-product): A = P rows (own-wave), B = V^T rows — within-wave LDS dep
    __builtin_amdgcn_s_setprio(1);
    bf16x8 pf0 = *reinterpret_cast<const bf16x8*>(&Ps[swz(16 * w + m, hi)]);
    bf16x8 pf1 = *reinterpret_cast<const bf16x8*>(&Ps[swz(16 * w + m, 4 + hi)]);
    #pragma unroll
    for (int dt = 0; dt < 4; ++dt) {
      bf16x8 vf0 = *reinterpret_cast<const bf16x8*>(&VsH[swz(dt * 16 + m, hi)]);
      bf16x8 vf1 = *reinterpret_cast<const bf16x8*>(&VsH[swz(dt * 16 + m, 4 + hi)]);
      o_[dt] = MFMA16(pf0, vf0, o_[dt]);
      o_[dt] = MFMA16(pf1, vf1, o_[dt]);
    }
    __builtin_amdgcn_s_setprio(0);

    // coalesced prob write: wave reads its own 16 Ps rows, 128-B global segments
    {
      const int pr = 16 * w + (ln >> 2);
      const int cs = (ln & 3) * 2;
      us8 v0 = *reinterpret_cast<const us8*>(&Ps[swz(pr, cs)]);
      us8 v1 = *reinterpret_cast<const us8*>(&Ps[swz(pr, cs + 1)]);
      const size_t gi = arow0 + (size_t)pr * L + (size_t)(kt * 64 + (ln & 3) * 16);
      if constexpr (IsF32<T>::value) {
        float* dst = (float*)aout + gi;
        *reinterpret_cast<float4*>(dst + 0) =
            make_float4(bf2f(v0[0]), bf2f(v0[1]), bf2f(v0[2]), bf2f(v0[3]));
        *reinterpret_cast<float4*>(dst + 4) =
            make_float4(bf2f(v0[4]), bf2f(v0[5]), bf2f(v0[6]), bf2f(v0[7]));
        *reinterpret_cast<float4*>(dst + 8) =
            make_float4(bf2f(v1[0]), bf2f(v1[1]), bf2f(v1[2]), bf2f(v1[3]));
        *reinterpret_cast<float4*>(dst + 12) =
            make_float4(bf2f(v1[4]), bf2f(v1[5]), bf2f(v1[6]), bf2f(v1[7]));
      } else {
        bf16* dst = (bf16*)aout + gi;
        *reinterpret_cast<uint4*>(dst + 0) = *reinterpret_cast<const uint4*>(&v0);
        *reinterpret_cast<uint4*>(dst + 8) = *reinterpret_cast<const uint4*>(&v1);
      }
    }
    __syncthreads();
  }

  // fully-masked region of causal heads: probs exactly 0 (coalesced)
  if (is_local) {
    const int pr = 16 * w + (ln >> 2);
    const size_t rbase = arow0 + (size_t)pr * L;
    for (int c = nkt * 64 + (ln & 3) * 16; c < L; c += 64) {
      if constexpr (IsF32<T>::value) {
        float* dst = (float*)aout + rbase + c;
        const float4 z4 = make_float4(0.f, 0.f, 0.f, 0.f);
        *reinterpret_cast<float4*>(dst + 0) = z4;
        *reinterpret_cast<float4*>(dst + 4) = z4;
        *reinterpret_cast<float4*>(dst + 8) = z4;
        *reinterpret_cast<float4*>(dst + 12) = z4;
      } else {
        bf16* dst = (bf16*)aout + rbase + c;
        const uint4 z4 = make_uint4(0u, 0u, 0u, 0u);
        *reinterpret_cast<uint4*>(dst + 0) = z4;
        *reinterpret_cast<uint4*>(dst + 8) = z4;
      }
    }
  }

  // AO [B,L,D] as bf16 hi plane (feeds 1-product out_proj)
  #pragma unroll
  for (int dt = 0; dt < 4; ++dt)
    #pragma unroll
    for (int r = 0; r < 4; ++r)
      AOh[((size_t)bb * L + q0 + 16 * w + 4 * hi + r) * D + h * HD + dt * 16 + m] =
          bfh(o_[dt][r]);
}

template<typename T>
static void launch_path(void* const* d_in, void* d_out, void* d_ws, hipStream_t stream) {
  const int want = IsF32<T>::value;
  const int* flag = (const int*)d_ws;
  ushort_t* Qh  = (ushort_t*)((char*)d_ws + 256);
  ushort_t* Ql  = Qh + 4194304;
  ushort_t* Kh  = Ql + 4194304;
  ushort_t* Kl  = Kh + 4194304;
  ushort_t* Vth = Kl + 4194304;
  ushort_t* AOh = Vth + 4194304;
  ushort_t* Woth = AOh + 4194304;         // dedicated 2 MB
  // total ws use ≈ 50.6 MB

  const T* x  = (const T*)d_in[0];
  const T* Wq = (const T*)d_in[1];
  const T* bq = (const T*)d_in[2];
  const T* Wk = (const T*)d_in[3];
  const T* bk = (const T*)d_in[4];
  const T* Wv = (const T*)d_in[5];
  const T* bv = (const T*)d_in[6];
  const T* Wo = (const T*)d_in[7];
  const T* bo = (const T*)d_in[8];
  const T* ls = (const T*)d_in[9];
  const T* gs = (const T*)d_in[10];

  T* out0   = (T*)d_out;
  T* attn_l = out0 + (size_t)B * L * D;
  T* attn_g = attn_l + (size_t)B * LH * L * L;
  // scratch inside the not-yet-written attn_g output region (dead after proj)
  ushort_t* xh  = (ushort_t*)attn_g;
  ushort_t* xl  = xh + 4194304;
  ushort_t* Wt3 = xh + 8388608;           // 3 mats x (h,l) planes

  constexpr int NSA = IsF32<T>::value ? 2 : 1;

  if constexpr (IsF32<T>::value)
    split_f32_kernel<<<1024, 256, 0, stream>>>(flag, want, (const float*)x, xh, xl, 1048576);
  transW_kernel<T><<<dim3(16, 16, 4), 256, 0, stream>>>(
      flag, Wq, Wk, Wv, Wo, Wt3, Woth, 2);
  const ushort_t* xA = IsF32<T>::value ? xh : (const ushort_t*)x;
  // QKV projection: 768 blocks (32 M-tiles x 8 N-tiles x 3 mats)
  gemm_kernel<T, NSA><<<768, 256, 0, stream>>>(
      flag, xA, xl, AOh, Wt3, Woth, bq, bk, bv, bo,
      Qh, Ql, Kh, Kl, Vth, out0, 0);
  attn_kernel<T><<<1024, 256, 0, stream>>>(
      flag, Qh, Ql, Kh, Kl, Vth, ls, gs, attn_l, attn_g, AOh);
  // output projection: 256 blocks (32 M-tiles x 8 N-tiles), z = 3
  gemm_kernel<T, NSA><<<256, 256, 0, stream>>>(
      flag, xA, xl, AOh, Wt3, Woth, bq, bk, bv, bo,
      Qh, Ql, Kh, Kl, Vth, out0, 3);
}

extern "C" void kernel_launch(void* const* d_in, const int* in_sizes, int n_in,
                              void* d_out, int out_size, void* d_ws, size_t ws_size,
                              hipStream_t stream) {
  int* flag = (int*)d_ws;
  detect_dtype_kernel<<<1, 64, 0, stream>>>((const unsigned short*)d_in[0], flag);
  launch_path<float>(d_in, d_out, d_ws, stream);
  launch_path<bf16>(d_in, d_out, d_ws, stream);
}

// Round 7
// 966.892 us; speedup vs baseline: 1.5287x; 1.0053x over previous
//
#include <hip/hip_runtime.h>
#include <hip/hip_bf16.h>

#define B 2
#define L 2048
#define D 1024
#define H 16
#define HD 64
#define LH 8
#define NEG_INF -1e30f

typedef __hip_bfloat16 bf16;
typedef unsigned short ushort_t;
typedef short bf16x8 __attribute__((ext_vector_type(8)));
typedef unsigned short us8 __attribute__((ext_vector_type(8)));
typedef float f32x4 __attribute__((ext_vector_type(4)));

#define MFMA16(a, b, c) __builtin_amdgcn_mfma_f32_16x16x32_bf16((a), (b), (c), 0, 0, 0)

#if defined(__has_builtin)
#if __has_builtin(__builtin_amdgcn_global_load_lds)
#define HAVE_GLOAD_LDS 1
#endif
#endif

template<typename T> struct IsF32;
template<> struct IsF32<float> { static constexpr int value = 1; };
template<> struct IsF32<bf16>  { static constexpr int value = 0; };

__device__ __forceinline__ float ldf(const float* p, size_t i) { return p[i]; }
__device__ __forceinline__ float ldf(const bf16* p, size_t i) { return __bfloat162float(p[i]); }

__device__ __forceinline__ float4 ld4(const float* p, size_t i) {
  return *reinterpret_cast<const float4*>(p + i);
}
__device__ __forceinline__ float4 ld4(const bf16* p, size_t i) {
  ushort4 u = *reinterpret_cast<const ushort4*>(p + i);
  float4 f;
  f.x = __uint_as_float(((unsigned)u.x) << 16);
  f.y = __uint_as_float(((unsigned)u.y) << 16);
  f.z = __uint_as_float(((unsigned)u.z) << 16);
  f.w = __uint_as_float(((unsigned)u.w) << 16);
  return f;
}
__device__ __forceinline__ ushort_t bfh(float v) {
  bf16 h = __float2bfloat16(v);
  return *reinterpret_cast<ushort_t*>(&h);
}
__device__ __forceinline__ float bf2f(ushort_t u) {
  return __uint_as_float(((unsigned)u) << 16);
}
__device__ __forceinline__ void stf(float* p, size_t i, float v) { p[i] = v; }
__device__ __forceinline__ void stf(bf16* p, size_t i, float v) { p[i] = __float2bfloat16(v); }

// XOR-swizzled LDS addressing: 64-ushort (128 B) rows, 8 slots of 8 ushorts (16 B).
// slot' = slot ^ (row & 7)  -> 16B-aligned ds_*_b128, bank-conflict-reduced.
__device__ __forceinline__ int swz(int row, int slot) {
  return row * 64 + (((slot ^ (row & 7)) & 7) << 3);
}
__device__ __forceinline__ int swzc(int row, int c) {   // per-ushort column c
  return row * 64 + (((((c >> 3) ^ row) & 7) << 3) | (c & 7));
}

#if defined(HAVE_GLOAD_LDS)
__device__ __forceinline__ void gload_lds16(const ushort_t* src, ushort_t* dst) {
  __builtin_amdgcn_global_load_lds(
      (const __attribute__((address_space(1))) unsigned int*)src,
      (__attribute__((address_space(3))) unsigned int*)dst, 16, 0, 0);
}
#endif

// Stage a 64x64 ushort tile (16 rows per wave) into swizzled LDS. LDS dest is
// linear; the XOR swizzle is applied to the GLOBAL source slot (rule #21).
__device__ __forceinline__ void stage64(const ushort_t* g, size_t gstride,
                                        ushort_t* lds, int w, int ln) {
  #pragma unroll
  for (int c = 0; c < 2; ++c) {
    const int row = 16 * w + 8 * c + (ln >> 3);
    const int slot = ((ln & 7) ^ row) & 7;
    const ushort_t* src = g + (size_t)row * gstride + slot * 8;
#if defined(HAVE_GLOAD_LDS)
    gload_lds16(src, lds + (size_t)(16 * w + 8 * c) * 64);
#else
    *reinterpret_cast<uint4*>(&lds[row * 64 + (ln & 7) * 8]) =
        *reinterpret_cast<const uint4*>(src);
#endif
  }
}

// Stage a 128-row x 64-ushort tile (32 rows per wave), global row stride 1024.
__device__ __forceinline__ void stage128(const ushort_t* g, ushort_t* lds,
                                         int w, int ln) {
  #pragma unroll
  for (int c = 0; c < 4; ++c) {
    const int row = 32 * w + 8 * c + (ln >> 3);
    const int slot = ((ln & 7) ^ row) & 7;
    const ushort_t* src = g + (size_t)row * 1024 + slot * 8;
#if defined(HAVE_GLOAD_LDS)
    gload_lds16(src, lds + (size_t)(32 * w + 8 * c) * 64);
#else
    *reinterpret_cast<uint4*>(&lds[row * 64 + (ln & 7) * 8]) =
        *reinterpret_cast<const uint4*>(src);
#endif
  }
}

// Runtime dtype detection: fp32 data reinterpreted as u16 pairs shows large
// "exponent" fields in low halves with prob ~1/3; bf16 N(0,1) never does.
__global__ void detect_dtype_kernel(const unsigned short* __restrict__ x,
                                    int* __restrict__ flag) {
  int bad = 0;
  for (int i = threadIdx.x; i < 1024; i += 64) {
    if (((x[i] >> 7) & 0xFF) >= 170) bad = 1;
  }
  unsigned long long m = __ballot(bad);
  if (threadIdx.x == 0) *flag = (m != 0ULL) ? 1 : 0;
}

// ---------------- prep: split fp32 array into bf16 hi/lo planes ----------------
__global__ __launch_bounds__(256)
void split_f32_kernel(const int* __restrict__ flag, int want,
                      const float* __restrict__ in,
                      ushort_t* __restrict__ hp, ushort_t* __restrict__ lp, int n4) {
  if (*flag != want) return;
  int i = blockIdx.x * 256 + threadIdx.x;
  const int stride = gridDim.x * 256;
  for (; i < n4; i += stride) {
    float4 v = *reinterpret_cast<const float4*>(in + 4 * (size_t)i);
    ushort4 h, l;
    h.x = bfh(v.x); l.x = bfh(v.x - bf2f(h.x));
    h.y = bfh(v.y); l.y = bfh(v.y - bf2f(h.y));
    h.z = bfh(v.z); l.z = bfh(v.z - bf2f(h.z));
    h.w = bfh(v.w); l.w = bfh(v.w - bf2f(h.w));
    *reinterpret_cast<ushort4*>(hp + 4 * (size_t)i) = h;
    *reinterpret_cast<ushort4*>(lp + 4 * (size_t)i) = l;
  }
}

// ---------------- prep: transpose W [K][N] -> Wt [N][K], split to bf16 hi/lo ----
// grid (16,16,4): z=0..2 -> Wq/Wk/Wv into base (+lo for z<lo_upto); z=3 -> Wo
// hi-only into baseWo.
template<typename T>
__global__ __launch_bounds__(256)
void transW_kernel(const int* __restrict__ flag,
                   const T* __restrict__ W0, const T* __restrict__ W1,
                   const T* __restrict__ W2, const T* __restrict__ W3,
                   ushort_t* __restrict__ base, ushort_t* __restrict__ baseWo,
                   int lo_upto) {
  if (*flag != IsF32<T>::value) return;
  const int z = blockIdx.z;
  const T* W = z == 0 ? W0 : (z == 1 ? W1 : (z == 2 ? W2 : W3));
  ushort_t* hp = (z < 3) ? (base + (size_t)z * 2097152) : baseWo;
  ushort_t* lp = hp + 1048576;
  const bool wl_ = IsF32<T>::value && (z < lo_upto);
  __shared__ float ts[64][69];
  const int k0 = blockIdx.x * 64, n0 = blockIdx.y * 64;
  const int t = threadIdx.x;
  #pragma unroll
  for (int p = 0; p < 4; ++p) {
    int r = p * 16 + (t >> 4);
    int c = (t & 15) * 4;
    float4 v = ld4(W, (size_t)(k0 + r) * D + n0 + c);
    ts[r][c] = v.x; ts[r][c + 1] = v.y; ts[r][c + 2] = v.z; ts[r][c + 3] = v.w;
  }
  __syncthreads();
  #pragma unroll
  for (int p = 0; p < 4; ++p) {
    int n = p * 16 + (t >> 4);
    int k4 = (t & 15) * 4;
    ushort4 h, l;
    float a0 = ts[k4][n], a1 = ts[k4 + 1][n], a2 = ts[k4 + 2][n], a3 = ts[k4 + 3][n];
    h.x = bfh(a0); l.x = bfh(a0 - bf2f(h.x));
    h.y = bfh(a1); l.y = bfh(a1 - bf2f(h.y));
    h.z = bfh(a2); l.z = bfh(a2 - bf2f(h.z));
    h.w = bfh(a3); l.w = bfh(a3 - bf2f(h.w));
    size_t o = (size_t)(n0 + n) * D + k0 + k4;
    *reinterpret_cast<ushort4*>(hp + o) = h;
    if (wl_) *reinterpret_cast<ushort4*>(lp + o) = l;
  }
}

// ---------------- Kernel 1/3: LDS-staged MFMA GEMM -----------------------------
// BM=128, BN=64, BK=64. 4 waves, each 32 rows x 64 cols (2x4 fragments).
// FULL (Q/K on fp32 path): 3-product split, 48 KB LDS, 3 blocks/CU.
// !FULL (V, out-proj, all bf16-path mats): 1-product, 24 KB LDS.
// zfix >= 0 selects the matrix; zfix < 0 -> z = swzid >> 9 (multi-mat launch).
template<typename T, int NSA, bool FULL>
__global__ __launch_bounds__(256, FULL ? 3 : 4)
void gemm_kernel(const int* __restrict__ flag,
                 const ushort_t* __restrict__ xA, const ushort_t* __restrict__ xAl,
                 const ushort_t* __restrict__ aoh,
                 const ushort_t* __restrict__ wbase, const ushort_t* __restrict__ woT,
                 const T* __restrict__ bq, const T* __restrict__ bk,
                 const T* __restrict__ bv, const T* __restrict__ bo,
                 ushort_t* __restrict__ qh, ushort_t* __restrict__ ql,
                 ushort_t* __restrict__ kh, ushort_t* __restrict__ kl,
                 ushort_t* __restrict__ vth, T* __restrict__ out0, int zfix) {
  if (*flag != IsF32<T>::value) return;
  // XCD-chunked bijective swizzle (gridDim.x divisible by 8)
  const int cpx = gridDim.x >> 3;
  const int swzid = ((int)blockIdx.x & 7) * cpx + ((int)blockIdx.x >> 3);
  const int mtile = swzid & 31;
  const int ntile = (swzid >> 5) & 15;
  const int z = (zfix >= 0) ? zfix : (swzid >> 9);
  const int m0 = mtile * 128, n0 = ntile * 64;

  const bool isOut = (z == 3);
  const ushort_t* Ah = isOut ? aoh : xA;
  const ushort_t* wh = isOut ? woT : (wbase + (size_t)z * 2097152);
  const ushort_t* wl = wh + 1048576;

  // LDS carve: AsH 8192us, BsH 4096us (+ lo planes when FULL)
  constexpr int LDSUS = FULL ? 24576 : 12288;
  __shared__ ushort_t lds[LDSUS];
  ushort_t* AsH = lds;
  ushort_t* BsH = lds + 8192;
  ushort_t* AsL = FULL ? (lds + 12288) : nullptr;
  ushort_t* BsL = FULL ? (lds + 20480) : nullptr;

  const int ln = threadIdx.x & 63, w = threadIdx.x >> 6;
  const int m = ln & 15, hi = ln >> 4;

  f32x4 acc[2][4] = {};

  for (int k0 = 0; k0 < 1024; k0 += 64) {
    stage128(Ah + (size_t)m0 * 1024 + k0, AsH, w, ln);
    stage64(wh + (size_t)n0 * 1024 + k0, 1024, BsH, w, ln);
    if constexpr (FULL) {
      stage128(xAl + (size_t)m0 * 1024 + k0, AsL, w, ln);
      stage64(wl + (size_t)n0 * 1024 + k0, 1024, BsL, w, ln);
    }
    __syncthreads();
    #pragma unroll
    for (int kc = 0; kc < 2; ++kc) {
      bf16x8 a_h[2], b_h[4];
      #pragma unroll
      for (int f = 0; f < 2; ++f)
        a_h[f] = *reinterpret_cast<const bf16x8*>(&AsH[swz(w * 32 + f * 16 + m, kc * 4 + hi)]);
      #pragma unroll
      for (int f = 0; f < 4; ++f)
        b_h[f] = *reinterpret_cast<const bf16x8*>(&BsH[swz(f * 16 + m, kc * 4 + hi)]);
      #pragma unroll
      for (int fr = 0; fr < 2; ++fr)
        #pragma unroll
        for (int fc = 0; fc < 4; ++fc)
          acc[fr][fc] = MFMA16(a_h[fr], b_h[fc], acc[fr][fc]);
      if constexpr (FULL) {
        bf16x8 a_l[2], b_l[4];
        #pragma unroll
        for (int f = 0; f < 2; ++f)
          a_l[f] = *reinterpret_cast<const bf16x8*>(&AsL[swz(w * 32 + f * 16 + m, kc * 4 + hi)]);
        #pragma unroll
        for (int f = 0; f < 4; ++f)
          b_l[f] = *reinterpret_cast<const bf16x8*>(&BsL[swz(f * 16 + m, kc * 4 + hi)]);
        #pragma unroll
        for (int fr = 0; fr < 2; ++fr)
          #pragma unroll
          for (int fc = 0; fc < 4; ++fc) {
            acc[fr][fc] = MFMA16(a_h[fr], b_l[fc], acc[fr][fc]);
            acc[fr][fc] = MFMA16(a_l[fr], b_h[fc], acc[fr][fc]);
          }
      }
    }
    __syncthreads();
  }

  // ---------------- epilogue ----------------
  #pragma unroll
  for (int fc = 0; fc < 4; ++fc) {
    const int col = n0 + fc * 16 + m;
    if (isOut) {
      const float bv_ = ldf(bo, (size_t)col);
      #pragma unroll
      for (int fr = 0; fr < 2; ++fr)
        #pragma unroll
        for (int r = 0; r < 4; ++r) {
          const int tok = m0 + w * 32 + fr * 16 + 4 * hi + r;
          stf(out0, (size_t)tok * D + col, acc[fr][fc][r] + bv_);
        }
    } else if (z == 2) {
      const int hh = col >> 6, d = col & 63;
      const float bv_ = ldf(bv, (size_t)col);
      #pragma unroll
      for (int fr = 0; fr < 2; ++fr) {
        const int tok0 = m0 + w * 32 + fr * 16 + 4 * hi;
        const int bb = tok0 >> 11, ll = tok0 & (L - 1);
        ushort4 hv;
        hv.x = bfh(acc[fr][fc][0] + bv_);
        hv.y = bfh(acc[fr][fc][1] + bv_);
        hv.z = bfh(acc[fr][fc][2] + bv_);
        hv.w = bfh(acc[fr][fc][3] + bv_);
        *reinterpret_cast<ushort4*>(
            &vth[((size_t)(bb * H + hh) * HD + d) * L + ll]) = hv;
      }
    } else {
      const int hh = col >> 6, d = col & 63;
      const float bv_ = ldf(z == 0 ? bq : bk, (size_t)col);
      ushort_t* oh = z == 0 ? qh : kh;
      ushort_t* ol = z == 0 ? ql : kl;
      #pragma unroll
      for (int fr = 0; fr < 2; ++fr)
        #pragma unroll
        for (int r = 0; r < 4; ++r) {
          const int tok = m0 + w * 32 + fr * 16 + 4 * hi + r;
          const int bb = tok >> 11, ll = tok & (L - 1);
          const float v = acc[fr][fc][r] + bv_;
          const size_t o = ((size_t)(bb * H + hh) * L + ll) * HD + d;
          const ushort_t hu = bfh(v);
          oh[o] = hu; ol[o] = bfh(v - bf2f(hu));
        }
    }
  }
}

// ---------------- Kernel 2: attention (2-phase prefetch dbuf) ------------------
// 1024 blocks of 256 (XCD-swizzled). Block = 64 q-rows (4 waves x 16, swapped
// layout: lane owns one q-row). K/V double-buffered in swizzled LDS via
// global_load_lds: next tile's loads issue BEFORE current compute, ONE barrier
// per tile (T3-minimal). Pass 1 hi-only QK; pass 2: 3-product QK, 1-product PV,
// coalesced prob writes from LDS.
template<typename T>
__global__ __launch_bounds__(256, 2)
void attn_kernel(const int* __restrict__ flag,
                 const ushort_t* __restrict__ Qh_g, const ushort_t* __restrict__ Ql_g,
                 const ushort_t* __restrict__ Kh_g, const ushort_t* __restrict__ Kl_g,
                 const ushort_t* __restrict__ Vth_g,
                 const T* __restrict__ lsp, const T* __restrict__ gsp,
                 T* __restrict__ attn_l, T* __restrict__ attn_g,
                 ushort_t* __restrict__ AOh) {
  if (*flag != IsF32<T>::value) return;
  const int bid = blockIdx.x;
  const int xcd = bid & 7, slot = bid >> 3;       // 128 slots
  const int bhg = xcd + 8 * (slot >> 5);          // 0..31 (b,h)
  const int strip_raw = slot & 31;
  const int bb = bhg >> 4, h = bhg & 15;
  const bool is_local = h < LH;
  const int strip = is_local ? (31 - strip_raw) : strip_raw;  // long strips first
  const int q0 = strip * 64;
  const int ln = threadIdx.x & 63, w = threadIdx.x >> 6;
  const int m = ln & 15, hi = ln >> 4;

  const float cscale =
      (is_local ? ldf(lsp, (size_t)0) : ldf(gsp, (size_t)0)) * 0.125f;
  const size_t bh_off = ((size_t)bb * H + h) * L * HD;
  const ushort_t* Qhb = Qh_g + bh_off;
  const ushort_t* Qlb = Ql_g + bh_off;
  const ushort_t* Khb = Kh_g + bh_off;
  const ushort_t* Klb = Kl_g + bh_off;
  const ushort_t* Vhb = Vth_g + bh_off;   // [HD][L] per (b,h)

  __shared__ ushort_t KsH[2][4096], KsL[2][4096], VsH[2][4096], Ps[4096]; // 56 KB

  // Q fragments (B-operand; persist whole kernel)
  bf16x8 qfh[2], qfl[2];
  {
    const size_t qb = (size_t)(q0 + 16 * w + m) * HD + hi * 8;
    qfh[0] = *reinterpret_cast<const bf16x8*>(Qhb + qb);
    qfh[1] = *reinterpret_cast<const bf16x8*>(Qhb + qb + 32);
    qfl[0] = *reinterpret_cast<const bf16x8*>(Qlb + qb);
    qfl[1] = *reinterpret_cast<const bf16x8*>(Qlb + qb + 32);
  }

  float m_ = NEG_INF, l_ = 0.f;
  const int nkt = is_local ? (strip + 1) : (L / 64);
  T* aout = is_local ? attn_l : attn_g;
  const size_t arow0 =
      ((size_t)(bb * LH + (is_local ? h : h - LH)) * L + q0) * L;

  // ---------------- pass 1: row max / sum (hi-only: 8 MFMA/tile) --------------
  stage64(Khb, HD, KsH[0], w, ln);
  __syncthreads();
  for (int kt = 0; kt < nkt; ++kt) {
    const int cur = kt & 1;
    if (kt + 1 < nkt)
      stage64(Khb + (size_t)((kt + 1) * 64) * HD, HD, KsH[cur ^ 1], w, ln);

    f32x4 s[4] = {};
    __builtin_amdgcn_s_setprio(1);
    #pragma unroll
    for (int nt = 0; nt < 4; ++nt) {
      #pragma unroll
      for (int kc = 0; kc < 2; ++kc) {
        bf16x8 kbh = *reinterpret_cast<const bf16x8*>(&KsH[cur][swz(nt * 16 + m, kc * 4 + hi)]);
        s[nt] = MFMA16(kbh, qfh[kc], s[nt]);
      }
    }
    __builtin_amdgcn_s_setprio(0);

    const bool dg = is_local && (kt == strip);
    #pragma unroll
    for (int nt = 0; nt < 4; ++nt)
      #pragma unroll
      for (int r = 0; r < 4; ++r) {
        float v = s[nt][r] * cscale;
        if (dg && (nt * 16 + 4 * hi + r > 16 * w + m)) v = NEG_INF;
        s[nt][r] = v;
      }

    float tm = NEG_INF;
    #pragma unroll
    for (int nt = 0; nt < 4; ++nt)
      #pragma unroll
      for (int r = 0; r < 4; ++r) tm = fmaxf(tm, s[nt][r]);
    tm = fmaxf(tm, __shfl_xor(tm, 16, 64));
    tm = fmaxf(tm, __shfl_xor(tm, 32, 64));
    const float mn = fmaxf(m_, tm);
    float sum = 0.f;
    #pragma unroll
    for (int nt = 0; nt < 4; ++nt)
      #pragma unroll
      for (int r = 0; r < 4; ++r) sum += __expf(s[nt][r] - mn);
    sum += __shfl_xor(sum, 16, 64);
    sum += __shfl_xor(sum, 32, 64);
    l_ = l_ * __expf(m_ - mn) + sum;
    m_ = mn;
    __syncthreads();   // drains prefetch; next tile ready
  }

  const float invl = 1.0f / l_;
  f32x4 o_[4] = {};

  // ---------------- pass 2: 3-product QK, probs, 1-product PV -----------------
  stage64(Khb, HD, KsH[0], w, ln);
  stage64(Klb, HD, KsL[0], w, ln);
  stage64(Vhb, L, VsH[0], w, ln);
  __syncthreads();
  for (int kt = 0; kt < nkt; ++kt) {
    const int cur = kt & 1;
    if (kt + 1 < nkt) {
      stage64(Khb + (size_t)((kt + 1) * 64) * HD, HD, KsH[cur ^ 1], w, ln);
      stage64(Klb + (size_t)((kt + 1) * 64) * HD, HD, KsL[cur ^ 1], w, ln);
      stage64(Vhb + (size_t)((kt + 1) * 64), L, VsH[cur ^ 1], w, ln);
    }

    f32x4 s[4] = {};
    __builtin_amdgcn_s_setprio(1);
    #pragma unroll
    for (int nt = 0; nt < 4; ++nt) {
      #pragma unroll
      for (int kc = 0; kc < 2; ++kc) {
        bf16x8 kbh = *reinterpret_cast<const bf16x8*>(&KsH[cur][swz(nt * 16 + m, kc * 4 + hi)]);
        bf16x8 kbl = *reinterpret_cast<const bf16x8*>(&KsL[cur][swz(nt * 16 + m, kc * 4 + hi)]);
        s[nt] = MFMA16(kbh, qfh[kc], s[nt]);
        s[nt] = MFMA16(kbl, qfh[kc], s[nt]);
        s[nt] = MFMA16(kbh, qfl[kc], s[nt]);
      }
    }
    __builtin_amdgcn_s_setprio(0);

    const bool dg = is_local && (kt == strip);
    #pragma unroll
    for (int nt = 0; nt < 4; ++nt) {
      float v0 = s[nt][0] * cscale, v1 = s[nt][1] * cscale;
      float v2 = s[nt][2] * cscale, v3 = s[nt][3] * cscale;
      if (dg) {
        const int kbq = nt * 16 + 4 * hi, qq = 16 * w + m;
        if (kbq + 0 > qq) v0 = NEG_INF;
        if (kbq + 1 > qq) v1 = NEG_INF;
        if (kbq + 2 > qq) v2 = NEG_INF;
        if (kbq + 3 > qq) v3 = NEG_INF;
      }
      ushort4 pk;
      pk.x = bfh(__expf(v0 - m_) * invl);
      pk.y = bfh(__expf(v1 - m_) * invl);
      pk.z = bfh(__expf(v2 - m_) * invl);
      pk.w = bfh(__expf(v3 - m_) * invl);
      *reinterpret_cast<ushort4*>(&Ps[swzc(16 * w + m, nt * 16 + 4 * hi)]) = pk;
    }

    // PV (1-product): A = P rows (own-wave), B = V^T rows — within-wave LDS dep
    __builtin_amdgcn_s_setprio(1);
    bf16x8 pf0 = *reinterpret_cast<const bf16x8*>(&Ps[swz(16 * w + m, hi)]);
    bf16x8 pf1 = *reinterpret_cast<const bf16x8*>(&Ps[swz(16 * w + m, 4 + hi)]);
    #pragma unroll
    for (int dt = 0; dt < 4; ++dt) {
      bf16x8 vf0 = *reinterpret_cast<const bf16x8*>(&VsH[cur][swz(dt * 16 + m, hi)]);
      bf16x8 vf1 = *reinterpret_cast<const bf16x8*>(&VsH[cur][swz(dt * 16 + m, 4 + hi)]);
      o_[dt] = MFMA16(pf0, vf0, o_[dt]);
      o_[dt] = MFMA16(pf1, vf1, o_[dt]);
    }
    __builtin_amdgcn_s_setprio(0);

    // coalesced prob write: wave reads its own 16 Ps rows, 128-B global segments
    {
      const int pr = 16 * w + (ln >> 2);
      const int cs = (ln & 3) * 2;
      us8 v0 = *reinterpret_cast<const us8*>(&Ps[swz(pr, cs)]);
      us8 v1 = *reinterpret_cast<const us8*>(&Ps[swz(pr, cs + 1)]);
      const size_t gi = arow0 + (size_t)pr * L + (size_t)(kt * 64 + (ln & 3) * 16);
      if constexpr (IsF32<T>::value) {
        float* dst = (float*)aout + gi;
        *reinterpret_cast<float4*>(dst + 0) =
            make_float4(bf2f(v0[0]), bf2f(v0[1]), bf2f(v0[2]), bf2f(v0[3]));
        *reinterpret_cast<float4*>(dst + 4) =
            make_float4(bf2f(v0[4]), bf2f(v0[5]), bf2f(v0[6]), bf2f(v0[7]));
        *reinterpret_cast<float4*>(dst + 8) =
            make_float4(bf2f(v1[0]), bf2f(v1[1]), bf2f(v1[2]), bf2f(v1[3]));
        *reinterpret_cast<float4*>(dst + 12) =
            make_float4(bf2f(v1[4]), bf2f(v1[5]), bf2f(v1[6]), bf2f(v1[7]));
      } else {
        bf16* dst = (bf16*)aout + gi;
        *reinterpret_cast<uint4*>(dst + 0) = *reinterpret_cast<const uint4*>(&v0);
        *reinterpret_cast<uint4*>(dst + 8) = *reinterpret_cast<const uint4*>(&v1);
      }
    }
    __syncthreads();   // drains prefetch; Ps safe to overwrite next tile
  }

  // fully-masked region of causal heads: probs exactly 0 (coalesced)
  if (is_local) {
    const int pr = 16 * w + (ln >> 2);
    const size_t rbase = arow0 + (size_t)pr * L;
    for (int c = nkt * 64 + (ln & 3) * 16; c < L; c += 64) {
      if constexpr (IsF32<T>::value) {
        float* dst = (float*)aout + rbase + c;
        const float4 z4 = make_float4(0.f, 0.f, 0.f, 0.f);
        *reinterpret_cast<float4*>(dst + 0) = z4;
        *reinterpret_cast<float4*>(dst + 4) = z4;
        *reinterpret_cast<float4*>(dst + 8) = z4;
        *reinterpret_cast<float4*>(dst + 12) = z4;
      } else {
        bf16* dst = (bf16*)aout + rbase + c;
        const uint4 z4 = make_uint4(0u, 0u, 0u, 0u);
        *reinterpret_cast<uint4*>(dst + 0) = z4;
        *reinterpret_cast<uint4*>(dst + 8) = z4;
      }
    }
  }

  // AO [B,L,D] as bf16 hi plane (feeds 1-product out_proj)
  #pragma unroll
  for (int dt = 0; dt < 4; ++dt)
    #pragma unroll
    for (int r = 0; r < 4; ++r)
      AOh[((size_t)bb * L + q0 + 16 * w + 4 * hi + r) * D + h * HD + dt * 16 + m] =
          bfh(o_[dt][r]);
}

template<typename T>
static void launch_path(void* const* d_in, void* d_out, void* d_ws, hipStream_t stream) {
  const int want = IsF32<T>::value;
  const int* flag = (const int*)d_ws;
  ushort_t* Qh  = (ushort_t*)((char*)d_ws + 256);
  ushort_t* Ql  = Qh + 4194304;
  ushort_t* Kh  = Ql + 4194304;
  ushort_t* Kl  = Kh + 4194304;
  ushort_t* Vth = Kl + 4194304;
  ushort_t* AOh = Vth + 4194304;
  ushort_t* Woth = AOh + 4194304;         // dedicated 2 MB
  // total ws use ≈ 50.6 MB

  const T* x  = (const T*)d_in[0];
  const T* Wq = (const T*)d_in[1];
  const T* bq = (const T*)d_in[2];
  const T* Wk = (const T*)d_in[3];
  const T* bk = (const T*)d_in[4];
  const T* Wv = (const T*)d_in[5];
  const T* bv = (const T*)d_in[6];
  const T* Wo = (const T*)d_in[7];
  const T* bo = (const T*)d_in[8];
  const T* ls = (const T*)d_in[9];
  const T* gs = (const T*)d_in[10];

  T* out0   = (T*)d_out;
  T* attn_l = out0 + (size_t)B * L * D;
  T* attn_g = attn_l + (size_t)B * LH * L * L;
  // scratch inside the not-yet-written attn_g output region (dead after proj)
  ushort_t* xh  = (ushort_t*)attn_g;
  ushort_t* xl  = xh + 4194304;
  ushort_t* Wt3 = xh + 8388608;           // 3 mats x (h,l) planes

  constexpr int NSA = IsF32<T>::value ? 2 : 1;

  if constexpr (IsF32<T>::value)
    split_f32_kernel<<<1024, 256, 0, stream>>>(flag, want, (const float*)x, xh, xl, 1048576);
  transW_kernel<T><<<dim3(16, 16, 4), 256, 0, stream>>>(
      flag, Wq, Wk, Wv, Wo, Wt3, Woth, 2);
  const ushort_t* xA = IsF32<T>::value ? xh : (const ushort_t*)x;

  if constexpr (IsF32<T>::value) {
    // Q,K: 3-product (1024 blocks = 32M x 16N x 2 mats); V: 1-product (512)
    gemm_kernel<T, NSA, true><<<1024, 256, 0, stream>>>(
        flag, xA, xl, AOh, Wt3, Woth, bq, bk, bv, bo,
        Qh, Ql, Kh, Kl, Vth, out0, -1);
    gemm_kernel<T, NSA, false><<<512, 256, 0, stream>>>(
        flag, xA, xl, AOh, Wt3, Woth, bq, bk, bv, bo,
        Qh, Ql, Kh, Kl, Vth, out0, 2);
  } else {
    // bf16 inputs exact: Q,K,V all 1-product (1536 blocks = 3 mats)
    gemm_kernel<T, NSA, false><<<1536, 256, 0, stream>>>(
        flag, xA, xl, AOh, Wt3, Woth, bq, bk, bv, bo,
        Qh, Ql, Kh, Kl, Vth, out0, -1);
  }
  attn_kernel<T><<<1024, 256, 0, stream>>>(
      flag, Qh, Ql, Kh, Kl, Vth, ls, gs, attn_l, attn_g, AOh);
  // output projection: 512 blocks (32M x 16N), z = 3
  gemm_kernel<T, NSA, false><<<512, 256, 0, stream>>>(
      flag, xA, xl, AOh, Wt3, Woth, bq, bk, bv, bo,
      Qh, Ql, Kh, Kl, Vth, out0, 3);
}

extern "C" void kernel_launch(void* const* d_in, const int* in_sizes, int n_in,
                              void* d_out, int out_size, void* d_ws, size_t ws_size,
                              hipStream_t stream) {
  int* flag = (int*)d_ws;
  detect_dtype_kernel<<<1, 64, 0, stream>>>((const unsigned short*)d_in[0], flag);
  launch_path<float>(d_in, d_out, d_ws, stream);
  launch_path<bf16>(d_in, d_out, d_ws, stream);
}

// Round 8
// 927.333 us; speedup vs baseline: 1.5939x; 1.0427x over previous
//
#include <hip/hip_runtime.h>
#include <hip/hip_bf16.h>

#define B 2
#define L 2048
#define D 1024
#define H 16
#define HD 64
#define LH 8
#define NEG_INF -1e30f

typedef __hip_bfloat16 bf16;
typedef unsigned short ushort_t;
typedef short bf16x8 __attribute__((ext_vector_type(8)));
typedef unsigned short us8 __attribute__((ext_vector_type(8)));
typedef float f32x4 __attribute__((ext_vector_type(4)));

#define MFMA16(a, b, c) __builtin_amdgcn_mfma_f32_16x16x32_bf16((a), (b), (c), 0, 0, 0)

#if defined(__has_builtin)
#if __has_builtin(__builtin_amdgcn_global_load_lds)
#define HAVE_GLOAD_LDS 1
#endif
#endif

template<typename T> struct IsF32;
template<> struct IsF32<float> { static constexpr int value = 1; };
template<> struct IsF32<bf16>  { static constexpr int value = 0; };

__device__ __forceinline__ float ldf(const float* p, size_t i) { return p[i]; }
__device__ __forceinline__ float ldf(const bf16* p, size_t i) { return __bfloat162float(p[i]); }

__device__ __forceinline__ float4 ld4(const float* p, size_t i) {
  return *reinterpret_cast<const float4*>(p + i);
}
__device__ __forceinline__ float4 ld4(const bf16* p, size_t i) {
  ushort4 u = *reinterpret_cast<const ushort4*>(p + i);
  float4 f;
  f.x = __uint_as_float(((unsigned)u.x) << 16);
  f.y = __uint_as_float(((unsigned)u.y) << 16);
  f.z = __uint_as_float(((unsigned)u.z) << 16);
  f.w = __uint_as_float(((unsigned)u.w) << 16);
  return f;
}
__device__ __forceinline__ ushort_t bfh(float v) {
  bf16 h = __float2bfloat16(v);
  return *reinterpret_cast<ushort_t*>(&h);
}
__device__ __forceinline__ float bf2f(ushort_t u) {
  return __uint_as_float(((unsigned)u) << 16);
}
__device__ __forceinline__ void stf(float* p, size_t i, float v) { p[i] = v; }
__device__ __forceinline__ void stf(bf16* p, size_t i, float v) { p[i] = __float2bfloat16(v); }

// XOR-swizzled LDS addressing: 64-ushort (128 B) rows, 8 slots of 8 ushorts (16 B).
__device__ __forceinline__ int swz(int row, int slot) {
  return row * 64 + (((slot ^ (row & 7)) & 7) << 3);
}
__device__ __forceinline__ int swzc(int row, int c) {   // per-ushort column c
  return row * 64 + (((((c >> 3) ^ row) & 7) << 3) | (c & 7));
}

#if defined(HAVE_GLOAD_LDS)
__device__ __forceinline__ void gload_lds16(const ushort_t* src, ushort_t* dst) {
  __builtin_amdgcn_global_load_lds(
      (const __attribute__((address_space(1))) unsigned int*)src,
      (__attribute__((address_space(3))) unsigned int*)dst, 16, 0, 0);
}
#endif

// Stage a 64x64 ushort tile (16 rows per wave) into swizzled LDS. LDS dest is
// linear; the XOR swizzle is applied to the GLOBAL source slot (rule #21).
__device__ __forceinline__ void stage64(const ushort_t* g, size_t gstride,
                                        ushort_t* lds, int w, int ln) {
  #pragma unroll
  for (int c = 0; c < 2; ++c) {
    const int row = 16 * w + 8 * c + (ln >> 3);
    const int slot = ((ln & 7) ^ row) & 7;
    const ushort_t* src = g + (size_t)row * gstride + slot * 8;
#if defined(HAVE_GLOAD_LDS)
    gload_lds16(src, lds + (size_t)(16 * w + 8 * c) * 64);
#else
    *reinterpret_cast<uint4*>(&lds[row * 64 + (ln & 7) * 8]) =
        *reinterpret_cast<const uint4*>(src);
#endif
  }
}

// Stage a 128-row x 64-ushort tile (32 rows per wave), global row stride 1024.
__device__ __forceinline__ void stage128(const ushort_t* g, ushort_t* lds,
                                         int w, int ln) {
  #pragma unroll
  for (int c = 0; c < 4; ++c) {
    const int row = 32 * w + 8 * c + (ln >> 3);
    const int slot = ((ln & 7) ^ row) & 7;
    const ushort_t* src = g + (size_t)row * 1024 + slot * 8;
#if defined(HAVE_GLOAD_LDS)
    gload_lds16(src, lds + (size_t)(32 * w + 8 * c) * 64);
#else
    *reinterpret_cast<uint4*>(&lds[row * 64 + (ln & 7) * 8]) =
        *reinterpret_cast<const uint4*>(src);
#endif
  }
}

// Runtime dtype detection: fp32 data reinterpreted as u16 pairs shows large
// "exponent" fields in low halves with prob ~1/3; bf16 N(0,1) never does.
__global__ void detect_dtype_kernel(const unsigned short* __restrict__ x,
                                    int* __restrict__ flag) {
  int bad = 0;
  for (int i = threadIdx.x; i < 1024; i += 64) {
    if (((x[i] >> 7) & 0xFF) >= 170) bad = 1;
  }
  unsigned long long m = __ballot(bad);
  if (threadIdx.x == 0) *flag = (m != 0ULL) ? 1 : 0;
}

// ---------------- prep: cast fp32 array to bf16 (hi plane only) ----------------
__global__ __launch_bounds__(256)
void cast_f32_kernel(const int* __restrict__ flag, int want,
                     const float* __restrict__ in,
                     ushort_t* __restrict__ hp, int n4) {
  if (*flag != want) return;
  int i = blockIdx.x * 256 + threadIdx.x;
  const int stride = gridDim.x * 256;
  for (; i < n4; i += stride) {
    float4 v = *reinterpret_cast<const float4*>(in + 4 * (size_t)i);
    ushort4 h;
    h.x = bfh(v.x); h.y = bfh(v.y); h.z = bfh(v.z); h.w = bfh(v.w);
    *reinterpret_cast<ushort4*>(hp + 4 * (size_t)i) = h;
  }
}

// ---------------- prep: transpose W [K][N] -> Wt [N][K] bf16 hi ----------------
// grid (16,16,4): z=0..2 -> Wq/Wk/Wv into base + z*2097152; z=3 -> Wo -> baseWo.
template<typename T>
__global__ __launch_bounds__(256)
void transW_kernel(const int* __restrict__ flag,
                   const T* __restrict__ W0, const T* __restrict__ W1,
                   const T* __restrict__ W2, const T* __restrict__ W3,
                   ushort_t* __restrict__ base, ushort_t* __restrict__ baseWo) {
  if (*flag != IsF32<T>::value) return;
  const int z = blockIdx.z;
  const T* W = z == 0 ? W0 : (z == 1 ? W1 : (z == 2 ? W2 : W3));
  ushort_t* hp = (z < 3) ? (base + (size_t)z * 2097152) : baseWo;
  __shared__ float ts[64][69];
  const int k0 = blockIdx.x * 64, n0 = blockIdx.y * 64;
  const int t = threadIdx.x;
  #pragma unroll
  for (int p = 0; p < 4; ++p) {
    int r = p * 16 + (t >> 4);
    int c = (t & 15) * 4;
    float4 v = ld4(W, (size_t)(k0 + r) * D + n0 + c);
    ts[r][c] = v.x; ts[r][c + 1] = v.y; ts[r][c + 2] = v.z; ts[r][c + 3] = v.w;
  }
  __syncthreads();
  #pragma unroll
  for (int p = 0; p < 4; ++p) {
    int n = p * 16 + (t >> 4);
    int k4 = (t & 15) * 4;
    ushort4 h;
    h.x = bfh(ts[k4][n]);
    h.y = bfh(ts[k4 + 1][n]);
    h.z = bfh(ts[k4 + 2][n]);
    h.w = bfh(ts[k4 + 3][n]);
    *reinterpret_cast<ushort4*>(&hp[(size_t)(n0 + n) * D + k0 + k4]) = h;
  }
}

// ---------------- Kernel 1/3: LDS-staged MFMA GEMM (2-phase dbuf) --------------
// BM=128, BN=64, BK=64, 1-product bf16. 4 waves, each 32 rows x 64 cols
// (2x4 fragments). Double-buffered LDS (48 KB, 3 blocks/CU), ONE barrier per
// K-step, stage-next-before-compute (T3-minimal).
// z=0/1: Q/K -> hi+lo split planes [B,H,L,HD] (exact split of fp32 acc).
// z=2: V -> transposed hi plane [B,H,HD,L]. z=3: out-proj -> T out.
template<typename T>
__global__ __launch_bounds__(256, 3)
void gemm_kernel(const int* __restrict__ flag,
                 const ushort_t* __restrict__ xA, const ushort_t* __restrict__ aoh,
                 const ushort_t* __restrict__ wbase, const ushort_t* __restrict__ woT,
                 const T* __restrict__ bq, const T* __restrict__ bk,
                 const T* __restrict__ bv, const T* __restrict__ bo,
                 ushort_t* __restrict__ qh, ushort_t* __restrict__ ql,
                 ushort_t* __restrict__ kh, ushort_t* __restrict__ kl,
                 ushort_t* __restrict__ vth, T* __restrict__ out0, int zfix) {
  if (*flag != IsF32<T>::value) return;
  // XCD-chunked bijective swizzle (gridDim.x divisible by 8)
  const int cpx = gridDim.x >> 3;
  const int swzid = ((int)blockIdx.x & 7) * cpx + ((int)blockIdx.x >> 3);
  const int mtile = swzid & 31;
  const int ntile = (swzid >> 5) & 15;
  const int z = (zfix >= 0) ? zfix : (swzid >> 9);
  const int m0 = mtile * 128, n0 = ntile * 64;

  const bool isOut = (z == 3);
  const ushort_t* Ah = isOut ? aoh : xA;
  const ushort_t* wh = isOut ? woT : (wbase + (size_t)z * 2097152);

  __shared__ ushort_t As[2][8192], Bs[2][4096];   // 48 KB

  const int ln = threadIdx.x & 63, w = threadIdx.x >> 6;
  const int m = ln & 15, hi = ln >> 4;

  f32x4 acc[2][4] = {};

  stage128(Ah + (size_t)m0 * 1024, As[0], w, ln);
  stage64(wh + (size_t)n0 * 1024, 1024, Bs[0], w, ln);
  __syncthreads();
  for (int step = 0; step < 16; ++step) {
    const int cur = step & 1;
    if (step < 15) {
      stage128(Ah + (size_t)m0 * 1024 + (step + 1) * 64, As[cur ^ 1], w, ln);
      stage64(wh + (size_t)n0 * 1024 + (step + 1) * 64, 1024, Bs[cur ^ 1], w, ln);
    }
    __builtin_amdgcn_s_setprio(1);
    #pragma unroll
    for (int kc = 0; kc < 2; ++kc) {
      bf16x8 a_h[2], b_h[4];
      #pragma unroll
      for (int f = 0; f < 2; ++f)
        a_h[f] = *reinterpret_cast<const bf16x8*>(&As[cur][swz(w * 32 + f * 16 + m, kc * 4 + hi)]);
      #pragma unroll
      for (int f = 0; f < 4; ++f)
        b_h[f] = *reinterpret_cast<const bf16x8*>(&Bs[cur][swz(f * 16 + m, kc * 4 + hi)]);
      #pragma unroll
      for (int fr = 0; fr < 2; ++fr)
        #pragma unroll
        for (int fc = 0; fc < 4; ++fc)
          acc[fr][fc] = MFMA16(a_h[fr], b_h[fc], acc[fr][fc]);
    }
    __builtin_amdgcn_s_setprio(0);
    __syncthreads();   // drains next-step staging; protects buf[cur] reads
  }

  // ---------------- epilogue ----------------
  #pragma unroll
  for (int fc = 0; fc < 4; ++fc) {
    const int col = n0 + fc * 16 + m;
    if (isOut) {
      const float bv_ = ldf(bo, (size_t)col);
      #pragma unroll
      for (int fr = 0; fr < 2; ++fr)
        #pragma unroll
        for (int r = 0; r < 4; ++r) {
          const int tok = m0 + w * 32 + fr * 16 + 4 * hi + r;
          stf(out0, (size_t)tok * D + col, acc[fr][fc][r] + bv_);
        }
    } else if (z == 2) {
      const int hh = col >> 6, d = col & 63;
      const float bv_ = ldf(bv, (size_t)col);
      #pragma unroll
      for (int fr = 0; fr < 2; ++fr) {
        const int tok0 = m0 + w * 32 + fr * 16 + 4 * hi;
        const int bb = tok0 >> 11, ll = tok0 & (L - 1);
        ushort4 hv;
        hv.x = bfh(acc[fr][fc][0] + bv_);
        hv.y = bfh(acc[fr][fc][1] + bv_);
        hv.z = bfh(acc[fr][fc][2] + bv_);
        hv.w = bfh(acc[fr][fc][3] + bv_);
        *reinterpret_cast<ushort4*>(
            &vth[((size_t)(bb * H + hh) * HD + d) * L + ll]) = hv;
      }
    } else {
      const int hh = col >> 6, d = col & 63;
      const float bv_ = ldf(z == 0 ? bq : bk, (size_t)col);
      ushort_t* oh = z == 0 ? qh : kh;
      ushort_t* ol = z == 0 ? ql : kl;
      #pragma unroll
      for (int fr = 0; fr < 2; ++fr)
        #pragma unroll
        for (int r = 0; r < 4; ++r) {
          const int tok = m0 + w * 32 + fr * 16 + 4 * hi + r;
          const int bb = tok >> 11, ll = tok & (L - 1);
          const float v = acc[fr][fc][r] + bv_;
          const size_t o = ((size_t)(bb * H + hh) * L + ll) * HD + d;
          const ushort_t hu = bfh(v);
          oh[o] = hu; ol[o] = bfh(v - bf2f(hu));
        }
    }
  }
}

// ---------------- Kernel 2: attention (K dbuf + mid-tile V barrier) ------------
// 1024 blocks of 256 (XCD-swizzled). Block = 64 q-rows (4 waves x 16, swapped
// layout: lane owns one q-row). K hi/lo double-buffered (prefetch next tile);
// V single-buffered, staged for the CURRENT tile at tile top — latency hides
// under QK+softmax, mid-tile barrier before PV. 48 KB LDS -> 3 blocks/CU.
// Pass 1 hi-only QK (m-errors cancel in exp(s-m)/l); pass 2: 3-product QK,
// 1-product PV, coalesced prob writes from LDS.
template<typename T>
__global__ __launch_bounds__(256, 3)
void attn_kernel(const int* __restrict__ flag,
                 const ushort_t* __restrict__ Qh_g, const ushort_t* __restrict__ Ql_g,
                 const ushort_t* __restrict__ Kh_g, const ushort_t* __restrict__ Kl_g,
                 const ushort_t* __restrict__ Vth_g,
                 const T* __restrict__ lsp, const T* __restrict__ gsp,
                 T* __restrict__ attn_l, T* __restrict__ attn_g,
                 ushort_t* __restrict__ AOh) {
  if (*flag != IsF32<T>::value) return;
  const int bid = blockIdx.x;
  const int xcd = bid & 7, slot = bid >> 3;       // 128 slots
  const int bhg = xcd + 8 * (slot >> 5);          // 0..31 (b,h)
  const int strip_raw = slot & 31;
  const int bb = bhg >> 4, h = bhg & 15;
  const bool is_local = h < LH;
  const int strip = is_local ? (31 - strip_raw) : strip_raw;  // long strips first
  const int q0 = strip * 64;
  const int ln = threadIdx.x & 63, w = threadIdx.x >> 6;
  const int m = ln & 15, hi = ln >> 4;

  const float cscale =
      (is_local ? ldf(lsp, (size_t)0) : ldf(gsp, (size_t)0)) * 0.125f;
  const size_t bh_off = ((size_t)bb * H + h) * L * HD;
  const ushort_t* Qhb = Qh_g + bh_off;
  const ushort_t* Qlb = Ql_g + bh_off;
  const ushort_t* Khb = Kh_g + bh_off;
  const ushort_t* Klb = Kl_g + bh_off;
  const ushort_t* Vhb = Vth_g + bh_off;   // [HD][L] per (b,h)

  __shared__ ushort_t KsH[2][4096], KsL[2][4096], VsH[4096], Ps[4096]; // 48 KB

  // Q fragments (B-operand; persist whole kernel)
  bf16x8 qfh[2], qfl[2];
  {
    const size_t qb = (size_t)(q0 + 16 * w + m) * HD + hi * 8;
    qfh[0] = *reinterpret_cast<const bf16x8*>(Qhb + qb);
    qfh[1] = *reinterpret_cast<const bf16x8*>(Qhb + qb + 32);
    qfl[0] = *reinterpret_cast<const bf16x8*>(Qlb + qb);
    qfl[1] = *reinterpret_cast<const bf16x8*>(Qlb + qb + 32);
  }

  float m_ = NEG_INF, l_ = 0.f;
  const int nkt = is_local ? (strip + 1) : (L / 64);
  T* aout = is_local ? attn_l : attn_g;
  const size_t arow0 =
      ((size_t)(bb * LH + (is_local ? h : h - LH)) * L + q0) * L;

  // ---------------- pass 1: row max / sum (hi-only: 8 MFMA/tile) --------------
  stage64(Khb, HD, KsH[0], w, ln);
  __syncthreads();
  for (int kt = 0; kt < nkt; ++kt) {
    const int cur = kt & 1;
    if (kt + 1 < nkt)
      stage64(Khb + (size_t)((kt + 1) * 64) * HD, HD, KsH[cur ^ 1], w, ln);

    f32x4 s[4] = {};
    __builtin_amdgcn_s_setprio(1);
    #pragma unroll
    for (int nt = 0; nt < 4; ++nt) {
      #pragma unroll
      for (int kc = 0; kc < 2; ++kc) {
        bf16x8 kbh = *reinterpret_cast<const bf16x8*>(&KsH[cur][swz(nt * 16 + m, kc * 4 + hi)]);
        s[nt] = MFMA16(kbh, qfh[kc], s[nt]);
      }
    }
    __builtin_amdgcn_s_setprio(0);

    const bool dg = is_local && (kt == strip);
    #pragma unroll
    for (int nt = 0; nt < 4; ++nt)
      #pragma unroll
      for (int r = 0; r < 4; ++r) {
        float v = s[nt][r] * cscale;
        if (dg && (nt * 16 + 4 * hi + r > 16 * w + m)) v = NEG_INF;
        s[nt][r] = v;
      }

    float tm = NEG_INF;
    #pragma unroll
    for (int nt = 0; nt < 4; ++nt)
      #pragma unroll
      for (int r = 0; r < 4; ++r) tm = fmaxf(tm, s[nt][r]);
    tm = fmaxf(tm, __shfl_xor(tm, 16, 64));
    tm = fmaxf(tm, __shfl_xor(tm, 32, 64));
    const float mn = fmaxf(m_, tm);
    float sum = 0.f;
    #pragma unroll
    for (int nt = 0; nt < 4; ++nt)
      #pragma unroll
      for (int r = 0; r < 4; ++r) sum += __expf(s[nt][r] - mn);
    sum += __shfl_xor(sum, 16, 64);
    sum += __shfl_xor(sum, 32, 64);
    l_ = l_ * __expf(m_ - mn) + sum;
    m_ = mn;
    __syncthreads();   // drains prefetch; next tile ready
  }

  const float invl = 1.0f / l_;
  f32x4 o_[4] = {};

  // ---------------- pass 2: 3-product QK, probs, 1-product PV -----------------
  stage64(Khb, HD, KsH[0], w, ln);
  stage64(Klb, HD, KsL[0], w, ln);
  __syncthreads();
  for (int kt = 0; kt < nkt; ++kt) {
    const int cur = kt & 1;
    if (kt + 1 < nkt) {
      stage64(Khb + (size_t)((kt + 1) * 64) * HD, HD, KsH[cur ^ 1], w, ln);
      stage64(Klb + (size_t)((kt + 1) * 64) * HD, HD, KsL[cur ^ 1], w, ln);
    }
    stage64(Vhb + (size_t)(kt * 64), L, VsH, w, ln);   // current tile's V

    f32x4 s[4] = {};
    __builtin_amdgcn_s_setprio(1);
    #pragma unroll
    for (int nt = 0; nt < 4; ++nt) {
      #pragma unroll
      for (int kc = 0; kc < 2; ++kc) {
        bf16x8 kbh = *reinterpret_cast<const bf16x8*>(&KsH[cur][swz(nt * 16 + m, kc * 4 + hi)]);
        bf16x8 kbl = *reinterpret_cast<const bf16x8*>(&KsL[cur][swz(nt * 16 + m, kc * 4 + hi)]);
        s[nt] = MFMA16(kbh, qfh[kc], s[nt]);
        s[nt] = MFMA16(kbl, qfh[kc], s[nt]);
        s[nt] = MFMA16(kbh, qfl[kc], s[nt]);
      }
    }
    __builtin_amdgcn_s_setprio(0);

    const bool dg = is_local && (kt == strip);
    #pragma unroll
    for (int nt = 0; nt < 4; ++nt) {
      float v0 = s[nt][0] * cscale, v1 = s[nt][1] * cscale;
      float v2 = s[nt][2] * cscale, v3 = s[nt][3] * cscale;
      if (dg) {
        const int kbq = nt * 16 + 4 * hi, qq = 16 * w + m;
        if (kbq + 0 > qq) v0 = NEG_INF;
        if (kbq + 1 > qq) v1 = NEG_INF;
        if (kbq + 2 > qq) v2 = NEG_INF;
        if (kbq + 3 > qq) v3 = NEG_INF;
      }
      ushort4 pk;
      pk.x = bfh(__expf(v0 - m_) * invl);
      pk.y = bfh(__expf(v1 - m_) * invl);
      pk.z = bfh(__expf(v2 - m_) * invl);
      pk.w = bfh(__expf(v3 - m_) * invl);
      *reinterpret_cast<ushort4*>(&Ps[swzc(16 * w + m, nt * 16 + 4 * hi)]) = pk;
    }
    __syncthreads();   // barrier1: V(t) resident, all Ps writes visible

    // PV (1-product): A = P rows (own-wave), B = V^T rows
    __builtin_amdgcn_s_setprio(1);
    bf16x8 pf0 = *reinterpret_cast<const bf16x8*>(&Ps[swz(16 * w + m, hi)]);
    bf16x8 pf1 = *reinterpret_cast<const bf16x8*>(&Ps[swz(16 * w + m, 4 + hi)]);
    #pragma unroll
    for (int dt = 0; dt < 4; ++dt) {
      bf16x8 vf0 = *reinterpret_cast<const bf16x8*>(&VsH[swz(dt * 16 + m, hi)]);
      bf16x8 vf1 = *reinterpret_cast<const bf16x8*>(&VsH[swz(dt * 16 + m, 4 + hi)]);
      o_[dt] = MFMA16(pf0, vf0, o_[dt]);
      o_[dt] = MFMA16(pf1, vf1, o_[dt]);
    }
    __builtin_amdgcn_s_setprio(0);

    // coalesced prob write: wave reads its own 16 Ps rows, 128-B global segments
    {
      const int pr = 16 * w + (ln >> 2);
      const int cs = (ln & 3) * 2;
      us8 v0 = *reinterpret_cast<const us8*>(&Ps[swz(pr, cs)]);
      us8 v1 = *reinterpret_cast<const us8*>(&Ps[swz(pr, cs + 1)]);
      const size_t gi = arow0 + (size_t)pr * L + (size_t)(kt * 64 + (ln & 3) * 16);
      if constexpr (IsF32<T>::value) {
        float* dst = (float*)aout + gi;
        *reinterpret_cast<float4*>(dst + 0) =
            make_float4(bf2f(v0[0]), bf2f(v0[1]), bf2f(v0[2]), bf2f(v0[3]));
        *reinterpret_cast<float4*>(dst + 4) =
            make_float4(bf2f(v0[4]), bf2f(v0[5]), bf2f(v0[6]), bf2f(v0[7]));
        *reinterpret_cast<float4*>(dst + 8) =
            make_float4(bf2f(v1[0]), bf2f(v1[1]), bf2f(v1[2]), bf2f(v1[3]));
        *reinterpret_cast<float4*>(dst + 12) =
            make_float4(bf2f(v1[4]), bf2f(v1[5]), bf2f(v1[6]), bf2f(v1[7]));
      } else {
        bf16* dst = (bf16*)aout + gi;
        *reinterpret_cast<uint4*>(dst + 0) = *reinterpret_cast<const uint4*>(&v0);
        *reinterpret_cast<uint4*>(dst + 8) = *reinterpret_cast<const uint4*>(&v1);
      }
    }
    __syncthreads();   // barrier2: VsH/Ps reads done before next tile's staging
  }

  // fully-masked region of causal heads: probs exactly 0 (coalesced)
  if (is_local) {
    const int pr = 16 * w + (ln >> 2);
    const size_t rbase = arow0 + (size_t)pr * L;
    for (int c = nkt * 64 + (ln & 3) * 16; c < L; c += 64) {
      if constexpr (IsF32<T>::value) {
        float* dst = (float*)aout + rbase + c;
        const float4 z4 = make_float4(0.f, 0.f, 0.f, 0.f);
        *reinterpret_cast<float4*>(dst + 0) = z4;
        *reinterpret_cast<float4*>(dst + 4) = z4;
        *reinterpret_cast<float4*>(dst + 8) = z4;
        *reinterpret_cast<float4*>(dst + 12) = z4;
      } else {
        bf16* dst = (bf16*)aout + rbase + c;
        const uint4 z4 = make_uint4(0u, 0u, 0u, 0u);
        *reinterpret_cast<uint4*>(dst + 0) = z4;
        *reinterpret_cast<uint4*>(dst + 8) = z4;
      }
    }
  }

  // AO [B,L,D] as bf16 hi plane (feeds 1-product out_proj)
  #pragma unroll
  for (int dt = 0; dt < 4; ++dt)
    #pragma unroll
    for (int r = 0; r < 4; ++r)
      AOh[((size_t)bb * L + q0 + 16 * w + 4 * hi + r) * D + h * HD + dt * 16 + m] =
          bfh(o_[dt][r]);
}

template<typename T>
static void launch_path(void* const* d_in, void* d_out, void* d_ws, hipStream_t stream) {
  const int want = IsF32<T>::value;
  const int* flag = (const int*)d_ws;
  ushort_t* Qh  = (ushort_t*)((char*)d_ws + 256);
  ushort_t* Ql  = Qh + 4194304;
  ushort_t* Kh  = Ql + 4194304;
  ushort_t* Kl  = Kh + 4194304;
  ushort_t* Vth = Kl + 4194304;
  ushort_t* AOh = Vth + 4194304;
  ushort_t* Woth = AOh + 4194304;         // dedicated 2 MB
  // total ws use ≈ 52.6 MB

  const T* x  = (const T*)d_in[0];
  const T* Wq = (const T*)d_in[1];
  const T* bq = (const T*)d_in[2];
  const T* Wk = (const T*)d_in[3];
  const T* bk = (const T*)d_in[4];
  const T* Wv = (const T*)d_in[5];
  const T* bv = (const T*)d_in[6];
  const T* Wo = (const T*)d_in[7];
  const T* bo = (const T*)d_in[8];
  const T* ls = (const T*)d_in[9];
  const T* gs = (const T*)d_in[10];

  T* out0   = (T*)d_out;
  T* attn_l = out0 + (size_t)B * L * D;
  T* attn_g = attn_l + (size_t)B * LH * L * L;
  // scratch inside the not-yet-written attn_g output region (dead after proj)
  ushort_t* xh  = (ushort_t*)attn_g;
  ushort_t* Wt3 = xh + 4194304;           // 3 mats hi planes (stride 2M kept)

  if constexpr (IsF32<T>::value)
    cast_f32_kernel<<<1024, 256, 0, stream>>>(flag, want, (const float*)x, xh, 1048576);
  transW_kernel<T><<<dim3(16, 16, 4), 256, 0, stream>>>(
      flag, Wq, Wk, Wv, Wo, Wt3, Woth);
  const ushort_t* xA = IsF32<T>::value ? xh : (const ushort_t*)x;

  // QKV projection: 1536 blocks = 32 M-tiles x 16 N-tiles x 3 mats
  gemm_kernel<T><<<1536, 256, 0, stream>>>(
      flag, xA, AOh, Wt3, Woth, bq, bk, bv, bo,
      Qh, Ql, Kh, Kl, Vth, out0, -1);
  attn_kernel<T><<<1024, 256, 0, stream>>>(
      flag, Qh, Ql, Kh, Kl, Vth, ls, gs, attn_l, attn_g, AOh);
  // output projection: 512 blocks (32M x 16N), z = 3
  gemm_kernel<T><<<512, 256, 0, stream>>>(
      flag, xA, AOh, Wt3, Woth, bq, bk, bv, bo,
      Qh, Ql, Kh, Kl, Vth, out0, 3);
}

extern "C" void kernel_launch(void* const* d_in, const int* in_sizes, int n_in,
                              void* d_out, int out_size, void* d_ws, size_t ws_size,
                              hipStream_t stream) {
  int* flag = (int*)d_ws;
  detect_dtype_kernel<<<1, 64, 0, stream>>>((const unsigned short*)d_in[0], flag);
  launch_path<float>(d_in, d_out, d_ws, stream);
  launch_path<bf16>(d_in, d_out, d_ws, stream);
}

// Round 9
// 921.129 us; speedup vs baseline: 1.6046x; 1.0067x over previous
//
#include <hip/hip_runtime.h>
#include <hip/hip_bf16.h>

#define B 2
#define L 2048
#define D 1024
#define H 16
#define HD 64
#define LH 8
#define NEG_INF -1e30f

typedef __hip_bfloat16 bf16;
typedef unsigned short ushort_t;
typedef short bf16x8 __attribute__((ext_vector_type(8)));
typedef unsigned short us8 __attribute__((ext_vector_type(8)));
typedef float f32x4 __attribute__((ext_vector_type(4)));

#define MFMA16(a, b, c) __builtin_amdgcn_mfma_f32_16x16x32_bf16((a), (b), (c), 0, 0, 0)

// Counted-vmcnt barrier (T4): wait own loads to depth N (stores keep flying),
// drain own LDS ops, pin scheduler (rule #18), then raw s_barrier.
#define WAITBAR(N) do {                                              \
    asm volatile("s_waitcnt vmcnt(" #N ") lgkmcnt(0)" ::: "memory"); \
    __builtin_amdgcn_sched_barrier(0);                               \
    __builtin_amdgcn_s_barrier();                                    \
  } while (0)

#if defined(__has_builtin)
#if __has_builtin(__builtin_amdgcn_global_load_lds)
#define HAVE_GLOAD_LDS 1
#endif
#endif

template<typename T> struct IsF32;
template<> struct IsF32<float> { static constexpr int value = 1; };
template<> struct IsF32<bf16>  { static constexpr int value = 0; };

__device__ __forceinline__ float ldf(const float* p, size_t i) { return p[i]; }
__device__ __forceinline__ float ldf(const bf16* p, size_t i) { return __bfloat162float(p[i]); }

__device__ __forceinline__ float4 ld4(const float* p, size_t i) {
  return *reinterpret_cast<const float4*>(p + i);
}
__device__ __forceinline__ float4 ld4(const bf16* p, size_t i) {
  ushort4 u = *reinterpret_cast<const ushort4*>(p + i);
  float4 f;
  f.x = __uint_as_float(((unsigned)u.x) << 16);
  f.y = __uint_as_float(((unsigned)u.y) << 16);
  f.z = __uint_as_float(((unsigned)u.z) << 16);
  f.w = __uint_as_float(((unsigned)u.w) << 16);
  return f;
}
__device__ __forceinline__ ushort_t bfh(float v) {
  bf16 h = __float2bfloat16(v);
  return *reinterpret_cast<ushort_t*>(&h);
}
__device__ __forceinline__ float bf2f(ushort_t u) {
  return __uint_as_float(((unsigned)u) << 16);
}
__device__ __forceinline__ void stf(float* p, size_t i, float v) { p[i] = v; }
__device__ __forceinline__ void stf(bf16* p, size_t i, float v) { p[i] = __float2bfloat16(v); }

// XOR-swizzled LDS addressing: 64-ushort (128 B) rows, 8 slots of 8 ushorts (16 B).
__device__ __forceinline__ int swz(int row, int slot) {
  return row * 64 + (((slot ^ (row & 7)) & 7) << 3);
}
__device__ __forceinline__ int swzc(int row, int c) {   // per-ushort column c
  return row * 64 + (((((c >> 3) ^ row) & 7) << 3) | (c & 7));
}

#if defined(HAVE_GLOAD_LDS)
__device__ __forceinline__ void gload_lds16(const ushort_t* src, ushort_t* dst) {
  __builtin_amdgcn_global_load_lds(
      (const __attribute__((address_space(1))) unsigned int*)src,
      (__attribute__((address_space(3))) unsigned int*)dst, 16, 0, 0);
}
#endif

// Stage a 64x64 ushort tile (16 rows per wave) into swizzled LDS. LDS dest is
// linear; the XOR swizzle is applied to the GLOBAL source slot (rule #21).
// Cost: 2 vmcnt ops per thread (with gload_lds).
__device__ __forceinline__ void stage64(const ushort_t* g, size_t gstride,
                                        ushort_t* lds, int w, int ln) {
  #pragma unroll
  for (int c = 0; c < 2; ++c) {
    const int row = 16 * w + 8 * c + (ln >> 3);
    const int slot = ((ln & 7) ^ row) & 7;
    const ushort_t* src = g + (size_t)row * gstride + slot * 8;
#if defined(HAVE_GLOAD_LDS)
    gload_lds16(src, lds + (size_t)(16 * w + 8 * c) * 64);
#else
    *reinterpret_cast<uint4*>(&lds[row * 64 + (ln & 7) * 8]) =
        *reinterpret_cast<const uint4*>(src);
#endif
  }
}

// Stage a 128-row x 64-ushort tile (32 rows per wave), global row stride 1024.
__device__ __forceinline__ void stage128(const ushort_t* g, ushort_t* lds,
                                         int w, int ln) {
  #pragma unroll
  for (int c = 0; c < 4; ++c) {
    const int row = 32 * w + 8 * c + (ln >> 3);
    const int slot = ((ln & 7) ^ row) & 7;
    const ushort_t* src = g + (size_t)row * 1024 + slot * 8;
#if defined(HAVE_GLOAD_LDS)
    gload_lds16(src, lds + (size_t)(32 * w + 8 * c) * 64);
#else
    *reinterpret_cast<uint4*>(&lds[row * 64 + (ln & 7) * 8]) =
        *reinterpret_cast<const uint4*>(src);
#endif
  }
}

// Runtime dtype detection: fp32 data reinterpreted as u16 pairs shows large
// "exponent" fields in low halves with prob ~1/3; bf16 N(0,1) never does.
__global__ void detect_dtype_kernel(const unsigned short* __restrict__ x,
                                    int* __restrict__ flag) {
  int bad = 0;
  for (int i = threadIdx.x; i < 1024; i += 64) {
    if (((x[i] >> 7) & 0xFF) >= 170) bad = 1;
  }
  unsigned long long m = __ballot(bad);
  if (threadIdx.x == 0) *flag = (m != 0ULL) ? 1 : 0;
}

// ---------------- prep: cast fp32 array to bf16 (hi plane only) ----------------
__global__ __launch_bounds__(256)
void cast_f32_kernel(const int* __restrict__ flag, int want,
                     const float* __restrict__ in,
                     ushort_t* __restrict__ hp, int n4) {
  if (*flag != want) return;
  int i = blockIdx.x * 256 + threadIdx.x;
  const int stride = gridDim.x * 256;
  for (; i < n4; i += stride) {
    float4 v = *reinterpret_cast<const float4*>(in + 4 * (size_t)i);
    ushort4 h;
    h.x = bfh(v.x); h.y = bfh(v.y); h.z = bfh(v.z); h.w = bfh(v.w);
    *reinterpret_cast<ushort4*>(hp + 4 * (size_t)i) = h;
  }
}

// ---------------- prep: transpose W [K][N] -> Wt [N][K] bf16 hi ----------------
// grid (16,16,4): z=0..2 -> Wq/Wk/Wv into base + z*2097152; z=3 -> Wo -> baseWo.
template<typename T>
__global__ __launch_bounds__(256)
void transW_kernel(const int* __restrict__ flag,
                   const T* __restrict__ W0, const T* __restrict__ W1,
                   const T* __restrict__ W2, const T* __restrict__ W3,
                   ushort_t* __restrict__ base, ushort_t* __restrict__ baseWo) {
  if (*flag != IsF32<T>::value) return;
  const int z = blockIdx.z;
  const T* W = z == 0 ? W0 : (z == 1 ? W1 : (z == 2 ? W2 : W3));
  ushort_t* hp = (z < 3) ? (base + (size_t)z * 2097152) : baseWo;
  __shared__ float ts[64][69];
  const int k0 = blockIdx.x * 64, n0 = blockIdx.y * 64;
  const int t = threadIdx.x;
  #pragma unroll
  for (int p = 0; p < 4; ++p) {
    int r = p * 16 + (t >> 4);
    int c = (t & 15) * 4;
    float4 v = ld4(W, (size_t)(k0 + r) * D + n0 + c);
    ts[r][c] = v.x; ts[r][c + 1] = v.y; ts[r][c + 2] = v.z; ts[r][c + 3] = v.w;
  }
  __syncthreads();
  #pragma unroll
  for (int p = 0; p < 4; ++p) {
    int n = p * 16 + (t >> 4);
    int k4 = (t & 15) * 4;
    ushort4 h;
    h.x = bfh(ts[k4][n]);
    h.y = bfh(ts[k4 + 1][n]);
    h.z = bfh(ts[k4 + 2][n]);
    h.w = bfh(ts[k4 + 3][n]);
    *reinterpret_cast<ushort4*>(&hp[(size_t)(n0 + n) * D + k0 + k4]) = h;
  }
}

// ---------------- Kernel 1/3: LDS-staged MFMA GEMM (2-phase dbuf) --------------
// BM=128, BN=64, BK=64, 1-product bf16. 4 waves, each 32 rows x 64 cols
// (2x4 fragments). Double-buffered LDS (48 KB, 3 blocks/CU), ONE barrier per
// K-step, stage-next-before-compute (T3-minimal).
// z=0/1: Q/K -> hi+lo split planes [B,H,L,HD] (exact split of fp32 acc).
// z=2: V -> transposed hi plane [B,H,HD,L]. z=3: out-proj -> T out.
template<typename T>
__global__ __launch_bounds__(256, 3)
void gemm_kernel(const int* __restrict__ flag,
                 const ushort_t* __restrict__ xA, const ushort_t* __restrict__ aoh,
                 const ushort_t* __restrict__ wbase, const ushort_t* __restrict__ woT,
                 const T* __restrict__ bq, const T* __restrict__ bk,
                 const T* __restrict__ bv, const T* __restrict__ bo,
                 ushort_t* __restrict__ qh, ushort_t* __restrict__ ql,
                 ushort_t* __restrict__ kh, ushort_t* __restrict__ kl,
                 ushort_t* __restrict__ vth, T* __restrict__ out0, int zfix) {
  if (*flag != IsF32<T>::value) return;
  // XCD-chunked bijective swizzle (gridDim.x divisible by 8)
  const int cpx = gridDim.x >> 3;
  const int swzid = ((int)blockIdx.x & 7) * cpx + ((int)blockIdx.x >> 3);
  const int mtile = swzid & 31;
  const int ntile = (swzid >> 5) & 15;
  const int z = (zfix >= 0) ? zfix : (swzid >> 9);
  const int m0 = mtile * 128, n0 = ntile * 64;

  const bool isOut = (z == 3);
  const ushort_t* Ah = isOut ? aoh : xA;
  const ushort_t* wh = isOut ? woT : (wbase + (size_t)z * 2097152);

  __shared__ ushort_t As[2][8192], Bs[2][4096];   // 48 KB

  const int ln = threadIdx.x & 63, w = threadIdx.x >> 6;
  const int m = ln & 15, hi = ln >> 4;

  f32x4 acc[2][4] = {};

  stage128(Ah + (size_t)m0 * 1024, As[0], w, ln);
  stage64(wh + (size_t)n0 * 1024, 1024, Bs[0], w, ln);
  __syncthreads();
  for (int step = 0; step < 16; ++step) {
    const int cur = step & 1;
    if (step < 15) {
      stage128(Ah + (size_t)m0 * 1024 + (step + 1) * 64, As[cur ^ 1], w, ln);
      stage64(wh + (size_t)n0 * 1024 + (step + 1) * 64, 1024, Bs[cur ^ 1], w, ln);
    }
    __builtin_amdgcn_s_setprio(1);
    #pragma unroll
    for (int kc = 0; kc < 2; ++kc) {
      bf16x8 a_h[2], b_h[4];
      #pragma unroll
      for (int f = 0; f < 2; ++f)
        a_h[f] = *reinterpret_cast<const bf16x8*>(&As[cur][swz(w * 32 + f * 16 + m, kc * 4 + hi)]);
      #pragma unroll
      for (int f = 0; f < 4; ++f)
        b_h[f] = *reinterpret_cast<const bf16x8*>(&Bs[cur][swz(f * 16 + m, kc * 4 + hi)]);
      #pragma unroll
      for (int fr = 0; fr < 2; ++fr)
        #pragma unroll
        for (int fc = 0; fc < 4; ++fc)
          acc[fr][fc] = MFMA16(a_h[fr], b_h[fc], acc[fr][fc]);
    }
    __builtin_amdgcn_s_setprio(0);
    __syncthreads();   // drains next-step staging; protects buf[cur] reads
  }

  // ---------------- epilogue ----------------
  #pragma unroll
  for (int fc = 0; fc < 4; ++fc) {
    const int col = n0 + fc * 16 + m;
    if (isOut) {
      const float bv_ = ldf(bo, (size_t)col);
      #pragma unroll
      for (int fr = 0; fr < 2; ++fr)
        #pragma unroll
        for (int r = 0; r < 4; ++r) {
          const int tok = m0 + w * 32 + fr * 16 + 4 * hi + r;
          stf(out0, (size_t)tok * D + col, acc[fr][fc][r] + bv_);
        }
    } else if (z == 2) {
      const int hh = col >> 6, d = col & 63;
      const float bv_ = ldf(bv, (size_t)col);
      #pragma unroll
      for (int fr = 0; fr < 2; ++fr) {
        const int tok0 = m0 + w * 32 + fr * 16 + 4 * hi;
        const int bb = tok0 >> 11, ll = tok0 & (L - 1);
        ushort4 hv;
        hv.x = bfh(acc[fr][fc][0] + bv_);
        hv.y = bfh(acc[fr][fc][1] + bv_);
        hv.z = bfh(acc[fr][fc][2] + bv_);
        hv.w = bfh(acc[fr][fc][3] + bv_);
        *reinterpret_cast<ushort4*>(
            &vth[((size_t)(bb * H + hh) * HD + d) * L + ll]) = hv;
      }
    } else {
      const int hh = col >> 6, d = col & 63;
      const float bv_ = ldf(z == 0 ? bq : bk, (size_t)col);
      ushort_t* oh = z == 0 ? qh : kh;
      ushort_t* ol = z == 0 ? ql : kl;
      #pragma unroll
      for (int fr = 0; fr < 2; ++fr)
        #pragma unroll
        for (int r = 0; r < 4; ++r) {
          const int tok = m0 + w * 32 + fr * 16 + 4 * hi + r;
          const int bb = tok >> 11, ll = tok & (L - 1);
          const float v = acc[fr][fc][r] + bv_;
          const size_t o = ((size_t)(bb * H + hh) * L + ll) * HD + d;
          const ushort_t hu = bfh(v);
          oh[o] = hu; ol[o] = bfh(v - bf2f(hu));
        }
    }
  }
}

// ---------------- Kernel 2: attention (counted-vmcnt raw barriers) -------------
// 1024 blocks of 256 (XCD-swizzled). Block = 64 q-rows (4 waves x 16, swapped
// layout: lane owns one q-row). K hi/lo double-buffered (prefetch next tile);
// V single-buffered for the CURRENT tile. Pass 2 uses raw s_barrier + COUNTED
// vmcnt (T4): prob global-stores are never drained in-loop — they retire
// asynchronously under the next tile's compute. Issue order per tile:
//   V(t)[2] -> K(t+1)[4] -> QK/softmax -> vmcnt(4) bar -> PV -> stores[4]
//   -> vmcnt(4) lgkm(0) bar      (drains K(t+1); stores keep flying)
template<typename T>
__global__ __launch_bounds__(256, 3)
void attn_kernel(const int* __restrict__ flag,
                 const ushort_t* __restrict__ Qh_g, const ushort_t* __restrict__ Ql_g,
                 const ushort_t* __restrict__ Kh_g, const ushort_t* __restrict__ Kl_g,
                 const ushort_t* __restrict__ Vth_g,
                 const T* __restrict__ lsp, const T* __restrict__ gsp,
                 T* __restrict__ attn_l, T* __restrict__ attn_g,
                 ushort_t* __restrict__ AOh) {
  if (*flag != IsF32<T>::value) return;
  const int bid = blockIdx.x;
  const int xcd = bid & 7, slot = bid >> 3;       // 128 slots
  const int bhg = xcd + 8 * (slot >> 5);          // 0..31 (b,h)
  const int strip_raw = slot & 31;
  const int bb = bhg >> 4, h = bhg & 15;
  const bool is_local = h < LH;
  const int strip = is_local ? (31 - strip_raw) : strip_raw;  // long strips first
  const int q0 = strip * 64;
  const int ln = threadIdx.x & 63, w = threadIdx.x >> 6;
  const int m = ln & 15, hi = ln >> 4;

  const float cscale =
      (is_local ? ldf(lsp, (size_t)0) : ldf(gsp, (size_t)0)) * 0.125f;
  const size_t bh_off = ((size_t)bb * H + h) * L * HD;
  const ushort_t* Qhb = Qh_g + bh_off;
  const ushort_t* Qlb = Ql_g + bh_off;
  const ushort_t* Khb = Kh_g + bh_off;
  const ushort_t* Klb = Kl_g + bh_off;
  const ushort_t* Vhb = Vth_g + bh_off;   // [HD][L] per (b,h)

  __shared__ ushort_t KsH[2][4096], KsL[2][4096], VsH[4096], Ps[4096]; // 48 KB

  // Q fragments (B-operand; persist whole kernel)
  bf16x8 qfh[2], qfl[2];
  {
    const size_t qb = (size_t)(q0 + 16 * w + m) * HD + hi * 8;
    qfh[0] = *reinterpret_cast<const bf16x8*>(Qhb + qb);
    qfh[1] = *reinterpret_cast<const bf16x8*>(Qhb + qb + 32);
    qfl[0] = *reinterpret_cast<const bf16x8*>(Qlb + qb);
    qfl[1] = *reinterpret_cast<const bf16x8*>(Qlb + qb + 32);
  }

  float m_ = NEG_INF, l_ = 0.f;
  const int nkt = is_local ? (strip + 1) : (L / 64);
  T* aout = is_local ? attn_l : attn_g;
  const size_t arow0 =
      ((size_t)(bb * LH + (is_local ? h : h - LH)) * L + q0) * L;

  // ---------------- pass 1: row max / sum (hi-only: 8 MFMA/tile) --------------
  stage64(Khb, HD, KsH[0], w, ln);
  __syncthreads();
  for (int kt = 0; kt < nkt; ++kt) {
    const int cur = kt & 1;
    if (kt + 1 < nkt)
      stage64(Khb + (size_t)((kt + 1) * 64) * HD, HD, KsH[cur ^ 1], w, ln);

    f32x4 s[4] = {};
    __builtin_amdgcn_s_setprio(1);
    #pragma unroll
    for (int nt = 0; nt < 4; ++nt) {
      #pragma unroll
      for (int kc = 0; kc < 2; ++kc) {
        bf16x8 kbh = *reinterpret_cast<const bf16x8*>(&KsH[cur][swz(nt * 16 + m, kc * 4 + hi)]);
        s[nt] = MFMA16(kbh, qfh[kc], s[nt]);
      }
    }
    __builtin_amdgcn_s_setprio(0);

    const bool dg = is_local && (kt == strip);
    #pragma unroll
    for (int nt = 0; nt < 4; ++nt)
      #pragma unroll
      for (int r = 0; r < 4; ++r) {
        float v = s[nt][r] * cscale;
        if (dg && (nt * 16 + 4 * hi + r > 16 * w + m)) v = NEG_INF;
        s[nt][r] = v;
      }

    float tm = NEG_INF;
    #pragma unroll
    for (int nt = 0; nt < 4; ++nt)
      #pragma unroll
      for (int r = 0; r < 4; ++r) tm = fmaxf(tm, s[nt][r]);
    tm = fmaxf(tm, __shfl_xor(tm, 16, 64));
    tm = fmaxf(tm, __shfl_xor(tm, 32, 64));
    const float mn = fmaxf(m_, tm);
    float sum = 0.f;
    #pragma unroll
    for (int nt = 0; nt < 4; ++nt)
      #pragma unroll
      for (int r = 0; r < 4; ++r) sum += __expf(s[nt][r] - mn);
    sum += __shfl_xor(sum, 16, 64);
    sum += __shfl_xor(sum, 32, 64);
    l_ = l_ * __expf(m_ - mn) + sum;
    m_ = mn;
    __syncthreads();   // drains prefetch; next tile ready
  }

  const float invl = 1.0f / l_;
  f32x4 o_[4] = {};

  // ---------------- pass 2: 3-product QK, probs, 1-product PV -----------------
  stage64(Khb, HD, KsH[0], w, ln);
  stage64(Klb, HD, KsL[0], w, ln);
  __syncthreads();   // K(0) fully resident
  for (int kt = 0; kt < nkt; ++kt) {
    const int cur = kt & 1;
    const bool pf = (kt + 1 < nkt);
    stage64(Vhb + (size_t)(kt * 64), L, VsH, w, ln);   // current tile's V [2]
    if (pf) {
      stage64(Khb + (size_t)((kt + 1) * 64) * HD, HD, KsH[cur ^ 1], w, ln);
      stage64(Klb + (size_t)((kt + 1) * 64) * HD, HD, KsL[cur ^ 1], w, ln);
    }

    f32x4 s[4] = {};
    __builtin_amdgcn_s_setprio(1);
    #pragma unroll
    for (int nt = 0; nt < 4; ++nt) {
      #pragma unroll
      for (int kc = 0; kc < 2; ++kc) {
        bf16x8 kbh = *reinterpret_cast<const bf16x8*>(&KsH[cur][swz(nt * 16 + m, kc * 4 + hi)]);
        bf16x8 kbl = *reinterpret_cast<const bf16x8*>(&KsL[cur][swz(nt * 16 + m, kc * 4 + hi)]);
        s[nt] = MFMA16(kbh, qfh[kc], s[nt]);
        s[nt] = MFMA16(kbl, qfh[kc], s[nt]);
        s[nt] = MFMA16(kbh, qfl[kc], s[nt]);
      }
    }
    __builtin_amdgcn_s_setprio(0);

    const bool dg = is_local && (kt == strip);
    #pragma unroll
    for (int nt = 0; nt < 4; ++nt) {
      float v0 = s[nt][0] * cscale, v1 = s[nt][1] * cscale;
      float v2 = s[nt][2] * cscale, v3 = s[nt][3] * cscale;
      if (dg) {
        const int kbq = nt * 16 + 4 * hi, qq = 16 * w + m;
        if (kbq + 0 > qq) v0 = NEG_INF;
        if (kbq + 1 > qq) v1 = NEG_INF;
        if (kbq + 2 > qq) v2 = NEG_INF;
        if (kbq + 3 > qq) v3 = NEG_INF;
      }
      ushort4 pk;
      pk.x = bfh(__expf(v0 - m_) * invl);
      pk.y = bfh(__expf(v1 - m_) * invl);
      pk.z = bfh(__expf(v2 - m_) * invl);
      pk.w = bfh(__expf(v3 - m_) * invl);
      *reinterpret_cast<ushort4*>(&Ps[swzc(16 * w + m, nt * 16 + 4 * hi)]) = pk;
    }
    // barrier1: V(t) resident (own V-loads are oldest after prior stores) and
    // Ps writes visible. K(t+1)'s 4 loads stay in flight when prefetching.
    if (pf) { WAITBAR(4); } else { WAITBAR(0); }

    // PV (1-product): A = P rows (own-wave), B = V^T rows
    __builtin_amdgcn_s_setprio(1);
    bf16x8 pf0 = *reinterpret_cast<const bf16x8*>(&Ps[swz(16 * w + m, hi)]);
    bf16x8 pf1 = *reinterpret_cast<const bf16x8*>(&Ps[swz(16 * w + m, 4 + hi)]);
    #pragma unroll
    for (int dt = 0; dt < 4; ++dt) {
      bf16x8 vf0 = *reinterpret_cast<const bf16x8*>(&VsH[swz(dt * 16 + m, hi)]);
      bf16x8 vf1 = *reinterpret_cast<const bf16x8*>(&VsH[swz(dt * 16 + m, 4 + hi)]);
      o_[dt] = MFMA16(pf0, vf0, o_[dt]);
      o_[dt] = MFMA16(pf1, vf1, o_[dt]);
    }
    __builtin_amdgcn_s_setprio(0);

    // coalesced prob write: wave reads its own 16 Ps rows, 128-B global segments
    {
      const int pr = 16 * w + (ln >> 2);
      const int cs = (ln & 3) * 2;
      us8 v0 = *reinterpret_cast<const us8*>(&Ps[swz(pr, cs)]);
      us8 v1 = *reinterpret_cast<const us8*>(&Ps[swz(pr, cs + 1)]);
      const size_t gi = arow0 + (size_t)pr * L + (size_t)(kt * 64 + (ln & 3) * 16);
      if constexpr (IsF32<T>::value) {
        float* dst = (float*)aout + gi;
        *reinterpret_cast<float4*>(dst + 0) =
            make_float4(bf2f(v0[0]), bf2f(v0[1]), bf2f(v0[2]), bf2f(v0[3]));
        *reinterpret_cast<float4*>(dst + 4) =
            make_float4(bf2f(v0[4]), bf2f(v0[5]), bf2f(v0[6]), bf2f(v0[7]));
        *reinterpret_cast<float4*>(dst + 8) =
            make_float4(bf2f(v1[0]), bf2f(v1[1]), bf2f(v1[2]), bf2f(v1[3]));
        *reinterpret_cast<float4*>(dst + 12) =
            make_float4(bf2f(v1[4]), bf2f(v1[5]), bf2f(v1[6]), bf2f(v1[7]));
      } else {
        bf16* dst = (bf16*)aout + gi;
        *reinterpret_cast<uint4*>(dst + 0) = *reinterpret_cast<const uint4*>(&v0);
        *reinterpret_cast<uint4*>(dst + 8) = *reinterpret_cast<const uint4*>(&v1);
      }
    }
    // barrier2: drain K(t+1) (next QK reads it); own Ps/Vs reads done (lgkm);
    // the 4 fresh prob-stores keep flying across the barrier.
    WAITBAR(4);
  }

  // fully-masked region of causal heads: probs exactly 0 (coalesced)
  if (is_local) {
    const int pr = 16 * w + (ln >> 2);
    const size_t rbase = arow0 + (size_t)pr * L;
    for (int c = nkt * 64 + (ln & 3) * 16; c < L; c += 64) {
      if constexpr (IsF32<T>::value) {
        float* dst = (float*)aout + rbase + c;
        const float4 z4 = make_float4(0.f, 0.f, 0.f, 0.f);
        *reinterpret_cast<float4*>(dst + 0) = z4;
        *reinterpret_cast<float4*>(dst + 4) = z4;
        *reinterpret_cast<float4*>(dst + 8) = z4;
        *reinterpret_cast<float4*>(dst + 12) = z4;
      } else {
        bf16* dst = (bf16*)aout + rbase + c;
        const uint4 z4 = make_uint4(0u, 0u, 0u, 0u);
        *reinterpret_cast<uint4*>(dst + 0) = z4;
        *reinterpret_cast<uint4*>(dst + 8) = z4;
      }
    }
  }

  // AO [B,L,D] as bf16 hi plane (feeds 1-product out_proj)
  #pragma unroll
  for (int dt = 0; dt < 4; ++dt)
    #pragma unroll
    for (int r = 0; r < 4; ++r)
      AOh[((size_t)bb * L + q0 + 16 * w + 4 * hi + r) * D + h * HD + dt * 16 + m] =
          bfh(o_[dt][r]);
}

template<typename T>
static void launch_path(void* const* d_in, void* d_out, void* d_ws, hipStream_t stream) {
  const int want = IsF32<T>::value;
  const int* flag = (const int*)d_ws;
  ushort_t* Qh  = (ushort_t*)((char*)d_ws + 256);
  ushort_t* Ql  = Qh + 4194304;
  ushort_t* Kh  = Ql + 4194304;
  ushort_t* Kl  = Kh + 4194304;
  ushort_t* Vth = Kl + 4194304;
  ushort_t* AOh = Vth + 4194304;
  ushort_t* Woth = AOh + 4194304;         // dedicated 2 MB
  // total ws use ≈ 52.6 MB

  const T* x  = (const T*)d_in[0];
  const T* Wq = (const T*)d_in[1];
  const T* bq = (const T*)d_in[2];
  const T* Wk = (const T*)d_in[3];
  const T* bk = (const T*)d_in[4];
  const T* Wv = (const T*)d_in[5];
  const T* bv = (const T*)d_in[6];
  const T* Wo = (const T*)d_in[7];
  const T* bo = (const T*)d_in[8];
  const T* ls = (const T*)d_in[9];
  const T* gs = (const T*)d_in[10];

  T* out0   = (T*)d_out;
  T* attn_l = out0 + (size_t)B * L * D;
  T* attn_g = attn_l + (size_t)B * LH * L * L;
  // scratch inside the not-yet-written attn_g output region (dead after proj)
  ushort_t* xh  = (ushort_t*)attn_g;
  ushort_t* Wt3 = xh + 4194304;           // 3 mats hi planes (stride 2M kept)

  if constexpr (IsF32<T>::value)
    cast_f32_kernel<<<1024, 256, 0, stream>>>(flag, want, (const float*)x, xh, 1048576);
  transW_kernel<T><<<dim3(16, 16, 4), 256, 0, stream>>>(
      flag, Wq, Wk, Wv, Wo, Wt3, Woth);
  const ushort_t* xA = IsF32<T>::value ? xh : (const ushort_t*)x;

  // QKV projection: 1536 blocks = 32 M-tiles x 16 N-tiles x 3 mats
  gemm_kernel<T><<<1536, 256, 0, stream>>>(
      flag, xA, AOh, Wt3, Woth, bq, bk, bv, bo,
      Qh, Ql, Kh, Kl, Vth, out0, -1);
  attn_kernel<T><<<1024, 256, 0, stream>>>(
      flag, Qh, Ql, Kh, Kl, Vth, ls, gs, attn_l, attn_g, AOh);
  // output projection: 512 blocks (32M x 16N), z = 3
  gemm_kernel<T><<<512, 256, 0, stream>>>(
      flag, xA, AOh, Wt3, Woth, bq, bk, bv, bo,
      Qh, Ql, Kh, Kl, Vth, out0, 3);
}

extern "C" void kernel_launch(void* const* d_in, const int* in_sizes, int n_in,
                              void* d_out, int out_size, void* d_ws, size_t ws_size,
                              hipStream_t stream) {
  int* flag = (int*)d_ws;
  detect_dtype_kernel<<<1, 64, 0, stream>>>((const unsigned short*)d_in[0], flag);
  launch_path<float>(d_in, d_out, d_ws, stream);
  launch_path<bf16>(d_in, d_out, d_ws, stream);
}